// Round 7
// baseline (356.779 us; speedup 1.0000x reference)
//
#include <hip/hip_runtime.h>
#include <math.h>

#define K_CNT 8
#define IMG_H 1024
#define IMG_W 1024
#define SW 608            // scratch row stride (floats); max region w = 606
#define SH 272            // scratch rows; max region h = 270
#define SLOT (SW * SH)    // floats per region slot

#define RG_H ((SH + 2) / 3)              // 91 3-row groups per region (mega hpass)
#define N_HITEMS (32 * RG_H)             // 2912
#define YTILES ((SH + 15) / 16)          // 17
#define XTILES ((SW + 255) / 256)        // 3
#define N_VITEMS (32 * YTILES * XTILES)  // 1632
#define N_CTILES ((4 * IMG_H * IMG_W) / 256)  // 16384

struct RegionMeta {
  int ys, ye, xs, xe;
  int skip, r, L;
  float dxp, dyp;
  int pad0, pad1, pad2;
};

// LDS bank swizzle: XOR f[8:6] into f[4:2]; keeps 16B blocks contiguous, spreads
// stride-32B window reads across all 8 bank-quads (else ~16-way conflict).
__device__ __forceinline__ int swz(int f) { return f ^ ((f >> 6) & 7) * 4; }

// ------------------------- mega-kernel phases -------------------------

__device__ __forceinline__ void gsync(int* bar)
{
  __syncthreads();
  if (threadIdx.x == 0) {
    __hip_atomic_fetch_add(bar, 1, __ATOMIC_RELEASE, __HIP_MEMORY_SCOPE_AGENT);
    while (__hip_atomic_load(bar, __ATOMIC_RELAXED, __HIP_MEMORY_SCOPE_AGENT) < (int)gridDim.x)
      __builtin_amdgcn_s_sleep(4);
    (void)__hip_atomic_load(bar, __ATOMIC_ACQUIRE, __HIP_MEMORY_SCOPE_AGENT);
  }
  __syncthreads();
}

__device__ void meta_phase(const float* __restrict__ sigp, const float* __restrict__ tnhp,
                           const int* __restrict__ ta, float* __restrict__ g3out,
                           RegionMeta* __restrict__ meta, float* smem)
{
  int bid = blockIdx.x;           // < 32: region i*K+k
  int k = bid & 7;
  int tid = threadIdx.x;
  float* gn = smem;               // 64
  float* g2 = smem + 64;          // 128
  int* bx = (int*)(smem + 192);   // 8

  if (tid < 8) bx[tid] = ta[bid * 8 + tid];
  __syncthreads();
  int ys0 = min(min(bx[1], bx[3]), min(bx[5], bx[7]));
  int ye0 = max(max(bx[1], bx[3]), max(bx[5], bx[7]));
  int xs0 = min(min(bx[0], bx[2]), min(bx[4], bx[6]));
  int xe0 = max(max(bx[0], bx[2]), max(bx[4], bx[6]));
  int h = ye0 - ys0, w = xe0 - xs0;

  // reference indexes flattened params by k only (batch-0 params for all i)
  float sig1 = sigp[k * 2 + 1];
  float t0 = tnhp[k * 2 + 0], t1 = tnhp[k * 2 + 1];

  float blur = ((sig1 + 1e-5f) * (float)h) * 0.5f;
  double kfac = 0.75 * sqrt(2.0 * M_PI);
  int ks = (int)floor((double)blur * kfac + 0.5);
  if (ks < 2) ks = 2;
  if ((ks & 1) == 0) ks += 1;
  int r_ = ks >> 1, P = r_ * 3, L = 3 * ks - 2;
  float dxp = (t0 * (float)h) * 0.2f;
  float dyp = (t1 * (float)h) * 0.2f;
  double eh = (double)P + fabs((double)dyp);
  double ew = (double)P + fabs((double)dxp);
  int ys = (int)fmax(fmin((double)ys0 - eh, (double)IMG_H), 0.0);
  int ye = (int)fmax(fmin((double)ye0 + eh, (double)IMG_H), 0.0);
  int xs = (int)fmax(fmin((double)xs0 - ew, (double)IMG_W), 0.0);
  int xe = (int)fmax(fmin((double)xe0 + ew, (double)IMG_W), 0.0);

  if (tid == 0) {
    RegionMeta m;
    m.ys = ys; m.ye = ye; m.xs = xs; m.xe = xe;
    m.skip = (h < 5 || w < 5) ? 1 : 0;
    m.r = r_; m.L = L; m.dxp = dxp; m.dyp = dyp;
    m.pad0 = m.pad1 = m.pad2 = 0;
    meta[bid] = m;
  }

  float mean = 0.5f * (float)(ks - 1);
  float inv = 1.0f / (2.0f * blur);
  if (tid < 64) {
    float gx = 0.f;
    if (tid < ks) { float d = ((float)tid - mean) * inv; gx = expf(-(d * d)); }
    float S = gx;
    #pragma unroll
    for (int off = 32; off > 0; off >>= 1) S += __shfl_xor(S, off);
    gn[tid] = (tid < ks) ? gx / S : 0.f;
  }
  __syncthreads();
  if (tid < 2 * ks - 1) {
    int a = tid;
    int blo = max(0, a - ks + 1), bhi = min(a, ks - 1);
    float s = 0.f;
    for (int b = blo; b <= bhi; ++b) s += gn[b] * gn[a - b];
    g2[a] = s;
  }
  __syncthreads();
  {
    int a = tid;
    float s = 0.f;
    if (a < L) {
      int blo = max(0, a - (2 * ks - 2)), bhi = min(a, ks - 1);
      for (int b = blo; b <= bhi; ++b) s += gn[b] * g2[a - b];
    }
    g3out[(size_t)bid * 256 + a] = s;   // zero-padded beyond L
  }
}

// hpass item: (region z, 3-row group). 256 threads = 3 rows x 76 chunks of 8 outputs.
__device__ void hpass_item(int item, const float* __restrict__ alpha,
                           const RegionMeta* __restrict__ meta,
                           const float* __restrict__ g3all,
                           float* __restrict__ tmpH, float* g3s, float* srow)
{
  int tid = threadIdx.x;
  int z = item / RG_H, rg = item - z * RG_H;
  RegionMeta m = meta[z];
  __syncthreads();                       // smem reuse guard
  g3s[tid] = g3all[(size_t)z * 256 + tid];
  int ch = min(m.ye - m.ys, SH), cw = min(m.xe - m.xs, SW);
  int ybase = rg * 3;
  int nrows = (!m.skip && ybase < ch) ? min(3, ch - ybase) : 0;
  int P = m.r * 3;
  int i = z >> 3;
  for (int s = tid; s < nrows * 208; s += 256) {
    int r = s / 208;
    int e = (s - r * 208) * 4;
    const float* row = alpha + ((size_t)i * IMG_H + (m.ys + ybase + r)) * IMG_W + m.xs;
    float4 v; float* vp = (float*)&v;
    #pragma unroll
    for (int u = 0; u < 4; ++u) { int c = e + u - P; vp[u] = (c >= 0 && c < cw) ? row[c] : 0.f; }
    *(float4*)(srow + r * 832 + swz(e)) = v;
  }
  __syncthreads();
  if (nrows) {
    int r = tid / 76, c = tid - (tid / 76) * 76;
    int x0 = 8 * c;
    if (r < nrows && x0 < cw) {
      const float* sp = srow + r * 832;
      float w[16], acc[8];
      #pragma unroll
      for (int q = 0; q < 4; ++q) *(float4*)(&w[4 * q]) = *(const float4*)(sp + swz(x0 + 4 * q));
      #pragma unroll
      for (int t = 0; t < 8; ++t) acc[t] = 0.f;
      int Lp = (m.L + 7) & ~7;
      for (int jj = 0; jj < Lp; jj += 16) {
        {
          float ga[8];
          *(float4*)(ga)     = *(const float4*)(g3s + jj);
          *(float4*)(ga + 4) = *(const float4*)(g3s + jj + 4);
          #pragma unroll
          for (int u = 0; u < 8; ++u) {
            float g = ga[u];
            #pragma unroll
            for (int t = 0; t < 8; ++t) acc[t] += g * w[(u + t) & 15];
          }
          *(float4*)(&w[0]) = *(const float4*)(sp + swz(x0 + jj + 16));
          *(float4*)(&w[4]) = *(const float4*)(sp + swz(x0 + jj + 20));
        }
        if (jj + 8 < Lp) {
          float ga[8];
          *(float4*)(ga)     = *(const float4*)(g3s + jj + 8);
          *(float4*)(ga + 4) = *(const float4*)(g3s + jj + 12);
          #pragma unroll
          for (int u = 0; u < 8; ++u) {
            float g = ga[u];
            #pragma unroll
            for (int t = 0; t < 8; ++t) acc[t] += g * w[(8 + u + t) & 15];
          }
          *(float4*)(&w[8])  = *(const float4*)(sp + swz(x0 + jj + 24));
          *(float4*)(&w[12]) = *(const float4*)(sp + swz(x0 + jj + 28));
        }
      }
      float* op = tmpH + (size_t)z * SLOT + (size_t)(ybase + r) * SW + x0;
      *(float4*)op       = make_float4(acc[0], acc[1], acc[2], acc[3]);
      *(float4*)(op + 4) = make_float4(acc[4], acc[5], acc[6], acc[7]);
    }
  }
}

// vpass item: (region z, 16-row tile, 256-col tile); 16 y-outputs per thread (ring w[32]).
__device__ void vpass_item(int item, const RegionMeta* __restrict__ meta,
                           const float* __restrict__ g3all,
                           const float* __restrict__ tmpH,
                           float* __restrict__ blurred, float* g3s)
{
  int tid = threadIdx.x;
  int z = item / (YTILES * XTILES);
  int rem = item - z * (YTILES * XTILES);
  int yg = rem / XTILES, xt = rem - (rem / XTILES) * XTILES;
  RegionMeta m = meta[z];
  __syncthreads();
  g3s[tid] = g3all[(size_t)z * 256 + tid];
  __syncthreads();
  if (m.skip) return;
  int ch = min(m.ye - m.ys, SH), cw = min(m.xe - m.xs, SW);
  int x = xt * 256 + tid;
  if (x >= cw) return;
  int y0 = yg * 16;
  if (y0 >= ch) return;
  int P = m.r * 3;
  int Lp = (m.L + 7) & ~7;
  const float* col = tmpH + (size_t)z * SLOT + x;
  int base = y0 - P;

  float w[32];
  if (base >= 0 && base + 31 < ch) {
    #pragma unroll
    for (int s = 0; s < 32; ++s) w[s] = col[(size_t)(base + s) * SW];
  } else {
    #pragma unroll
    for (int s = 0; s < 32; ++s) {
      int rr = base + s;
      w[s] = (rr >= 0 && rr < ch) ? col[(size_t)rr * SW] : 0.f;
    }
  }
  float acc[16];
  #pragma unroll
  for (int v = 0; v < 16; ++v) acc[v] = 0.f;

  for (int jj = 0; jj < Lp; jj += 32) {
    #define VPH(PH)                                                          \
    if (jj + (PH) < Lp) {                                                    \
      float ga[8];                                                           \
      *(float4*)(ga)     = *(const float4*)(g3s + jj + (PH));                \
      *(float4*)(ga + 4) = *(const float4*)(g3s + jj + (PH) + 4);            \
      _Pragma("unroll")                                                      \
      for (int u = 0; u < 8; ++u) {                                          \
        float g = ga[u];                                                     \
        _Pragma("unroll")                                                    \
        for (int v = 0; v < 16; ++v) acc[v] += g * w[((PH) + u + v) & 31];   \
      }                                                                      \
      int rb = base + jj + (PH) + 32;                                        \
      if (rb >= 0 && rb + 7 < ch) {                                          \
        _Pragma("unroll")                                                    \
        for (int q = 0; q < 8; ++q) w[((PH) + q) & 31] = col[(size_t)(rb + q) * SW]; \
      } else {                                                               \
        _Pragma("unroll")                                                    \
        for (int q = 0; q < 8; ++q) {                                        \
          int rr = rb + q;                                                   \
          w[((PH) + q) & 31] = (rr >= 0 && rr < ch) ? col[(size_t)rr * SW] : 0.f; \
        }                                                                    \
      }                                                                      \
    }
    VPH(0) VPH(8) VPH(16) VPH(24)
    #undef VPH
  }

  float* op = blurred + (size_t)z * SLOT + (size_t)y0 * SW + x;
  #pragma unroll
  for (int v = 0; v < 16; ++v)
    if (y0 + v < ch) op[(size_t)v * SW] = acc[v];
}

__device__ void composite_phase(const RegionMeta* __restrict__ meta,
                                const float* __restrict__ blurred,
                                float* __restrict__ sg, float* __restrict__ sl,
                                float* smem)
{
  RegionMeta* ms = (RegionMeta*)smem;
  {
    const int* src = (const int*)meta;
    int* dst = (int*)ms;
    for (int a = threadIdx.x; a < 32 * (int)(sizeof(RegionMeta) / 4); a += 256) dst[a] = src[a];
  }
  __syncthreads();
  for (int tile = blockIdx.x; tile < N_CTILES; tile += gridDim.x) {
    int idx = tile * 256 + (int)threadIdx.x;
    int x = idx & (IMG_W - 1);
    int y = (idx >> 10) & (IMG_H - 1);
    int i = idx >> 20;
    float sgv = 0.f, slv = 0.f;
    bool got = false;
    for (int k = K_CNT - 1; k >= 0; --k) {
      const RegionMeta& m = ms[i * K_CNT + k];
      if (m.skip) continue;
      int ch = min(m.ye - m.ys, SH), cw = min(m.xe - m.xs, SW);
      int ly = y - m.ys, lx = x - m.xs;
      if (ly < 0 || ly >= ch || lx < 0 || lx >= cw) continue;
      float sy = (float)ly - m.dyp;
      float sx = (float)lx - m.dxp;
      float x0f = floorf(sx), y0f = floorf(sy);
      float wx = sx - x0f, wy = sy - y0f;
      int x0 = (int)x0f, y0 = (int)y0f;
      const float* bl = blurred + (size_t)(i * K_CNT + k) * SLOT;
      float v00 = (y0 >= 0 && y0 < ch && x0 >= 0 && x0 < cw) ? bl[y0 * SW + x0] : 0.f;
      float v01 = (y0 >= 0 && y0 < ch && x0 + 1 >= 0 && x0 + 1 < cw) ? bl[y0 * SW + x0 + 1] : 0.f;
      float v10 = (y0 + 1 >= 0 && y0 + 1 < ch && x0 >= 0 && x0 < cw) ? bl[(y0 + 1) * SW + x0] : 0.f;
      float v11 = (y0 + 1 >= 0 && y0 + 1 < ch && x0 + 1 >= 0 && x0 + 1 < cw) ? bl[(y0 + 1) * SW + x0 + 1] : 0.f;
      float v = (1.f - wy) * ((1.f - wx) * v00 + wx * v01) + wy * ((1.f - wx) * v10 + wx * v11);
      if (!got) { sgv = v; got = true; }
      if (v > 0.f) { slv = (float)(k + 1); break; }
    }
    sg[idx] = sgv;
    sl[idx] = slv;
  }
}

__global__ __launch_bounds__(256, 6) void mega_kernel(
    const float* __restrict__ alpha, const float* __restrict__ sigp,
    const float* __restrict__ tnhp, const int* __restrict__ ta,
    RegionMeta* meta, float* g3all, float* tmpH, float* blurred,
    float* sg, float* sl, int* bars)
{
  __shared__ __align__(16) float g3s[256];
  __shared__ __align__(16) float smem[3 * 832];

  if (blockIdx.x < 32) meta_phase(sigp, tnhp, ta, g3all, meta, smem);
  gsync(&bars[0]);
  for (int it = blockIdx.x; it < N_HITEMS; it += gridDim.x)
    hpass_item(it, alpha, meta, g3all, tmpH, g3s, smem);
  gsync(&bars[1]);
  for (int it = blockIdx.x; it < N_VITEMS; it += gridDim.x)
    vpass_item(it, meta, g3all, tmpH, blurred, g3s);
  gsync(&bars[2]);
  composite_phase(meta, blurred, sg, sl, smem);
}

// ------------------------- fallback path (round-5 kernels) -------------------------

__global__ void meta_kernel(const float* __restrict__ sigp,
                            const float* __restrict__ tnhp,
                            const int* __restrict__ ta,
                            float* __restrict__ g3out,
                            RegionMeta* __restrict__ meta)
{
  int bid = blockIdx.x;
  int k = bid % K_CNT;
  int lane = threadIdx.x;
  __shared__ int bx[8];
  if (lane < 8) bx[lane] = ta[bid * 8 + lane];
  __syncthreads();
  int ys0 = min(min(bx[1], bx[3]), min(bx[5], bx[7]));
  int ye0 = max(max(bx[1], bx[3]), max(bx[5], bx[7]));
  int xs0 = min(min(bx[0], bx[2]), min(bx[4], bx[6]));
  int xe0 = max(max(bx[0], bx[2]), max(bx[4], bx[6]));
  int h = ye0 - ys0, w = xe0 - xs0;
  float sig1 = sigp[k * 2 + 1];
  float t0 = tnhp[k * 2 + 0], t1 = tnhp[k * 2 + 1];
  float blur = ((sig1 + 1e-5f) * (float)h) * 0.5f;
  double kfac = 0.75 * sqrt(2.0 * M_PI);
  int ks = (int)floor((double)blur * kfac + 0.5);
  if (ks < 2) ks = 2;
  if ((ks & 1) == 0) ks += 1;
  int r = ks >> 1, P = r * 3, L = 3 * ks - 2;
  float dxp = (t0 * (float)h) * 0.2f;
  float dyp = (t1 * (float)h) * 0.2f;
  double eh = (double)P + fabs((double)dyp);
  double ew = (double)P + fabs((double)dxp);
  int ys = (int)fmax(fmin((double)ys0 - eh, (double)IMG_H), 0.0);
  int ye = (int)fmax(fmin((double)ye0 + eh, (double)IMG_H), 0.0);
  int xs = (int)fmax(fmin((double)xs0 - ew, (double)IMG_W), 0.0);
  int xe = (int)fmax(fmin((double)xe0 + ew, (double)IMG_W), 0.0);
  int skip = (h < 5 || w < 5) ? 1 : 0;
  if (lane == 0) {
    RegionMeta m;
    m.ys = ys; m.ye = ye; m.xs = xs; m.xe = xe;
    m.skip = skip; m.r = r; m.L = L;
    m.dxp = dxp; m.dyp = dyp;
    m.pad0 = m.pad1 = m.pad2 = 0;
    meta[bid] = m;
  }
  float mean = 0.5f * (float)(ks - 1);
  float inv = 1.0f / (2.0f * blur);
  float gx = 0.f;
  if (lane < ks) { float d = ((float)lane - mean) * inv; gx = expf(-(d * d)); }
  float S = gx;
  #pragma unroll
  for (int off = 32; off > 0; off >>= 1) S += __shfl_xor(S, off);
  __shared__ float gn[64];
  gn[lane] = (lane < ks) ? gx / S : 0.f;
  __syncthreads();
  __shared__ float g2[128];
  for (int a = lane; a < 2 * ks - 1; a += 64) {
    int blo = max(0, a - ks + 1), bhi = min(a, ks - 1);
    float s = 0.f;
    for (int b = blo; b <= bhi; ++b) s += gn[b] * gn[a - b];
    g2[a] = s;
  }
  __syncthreads();
  float* g3 = g3out + (size_t)bid * 256;
  for (int a = lane; a < 256; a += 64) {
    float s = 0.f;
    if (a < L) {
      int blo = max(0, a - (2 * ks - 2)), bhi = min(a, ks - 1);
      for (int b = blo; b <= bhi; ++b) s += gn[b] * g2[a - b];
    }
    g3[a] = s;
  }
}

__global__ __launch_bounds__(256) void fb_hpass(const float* __restrict__ alpha,
                             const RegionMeta* __restrict__ meta,
                             const float* __restrict__ g3all,
                             float* __restrict__ tmpH, int kk)
{
  __shared__ __align__(16) float g3s[256];
  __shared__ __align__(16) float srow[3 * 832];
  int z = blockIdx.y;
  int reg = z * K_CNT + kk;
  int tid = threadIdx.x;
  RegionMeta m = meta[reg];
  g3s[tid] = g3all[(size_t)reg * 256 + tid];
  int ch = min(m.ye - m.ys, SH), cw = min(m.xe - m.xs, SW);
  int ybase = blockIdx.x * 3;
  int nrows = (!m.skip && ybase < ch) ? min(3, ch - ybase) : 0;
  int P = m.r * 3;
  for (int s = tid; s < nrows * 208; s += 256) {
    int r = s / 208;
    int e = (s - r * 208) * 4;
    const float* row = alpha + ((size_t)z * IMG_H + (m.ys + ybase + r)) * IMG_W + m.xs;
    float4 v; float* vp = (float*)&v;
    #pragma unroll
    for (int u = 0; u < 4; ++u) { int c = e + u - P; vp[u] = (c >= 0 && c < cw) ? row[c] : 0.f; }
    *(float4*)(srow + r * 832 + swz(e)) = v;
  }
  __syncthreads();
  if (!nrows) return;
  int r = tid / 76, c = tid - (tid / 76) * 76;
  int x0 = 8 * c;
  if (r >= nrows || x0 >= cw) return;
  const float* sp = srow + r * 832;
  float w[16], acc[8];
  #pragma unroll
  for (int q = 0; q < 4; ++q) *(float4*)(&w[4 * q]) = *(const float4*)(sp + swz(x0 + 4 * q));
  #pragma unroll
  for (int t = 0; t < 8; ++t) acc[t] = 0.f;
  int Lp = (m.L + 7) & ~7;
  for (int jj = 0; jj < Lp; jj += 16) {
    {
      float ga[8];
      *(float4*)(ga) = *(const float4*)(g3s + jj);
      *(float4*)(ga + 4) = *(const float4*)(g3s + jj + 4);
      #pragma unroll
      for (int u = 0; u < 8; ++u) {
        float g = ga[u];
        #pragma unroll
        for (int t = 0; t < 8; ++t) acc[t] += g * w[(u + t) & 15];
      }
      *(float4*)(&w[0]) = *(const float4*)(sp + swz(x0 + jj + 16));
      *(float4*)(&w[4]) = *(const float4*)(sp + swz(x0 + jj + 20));
    }
    if (jj + 8 < Lp) {
      float ga[8];
      *(float4*)(ga) = *(const float4*)(g3s + jj + 8);
      *(float4*)(ga + 4) = *(const float4*)(g3s + jj + 12);
      #pragma unroll
      for (int u = 0; u < 8; ++u) {
        float g = ga[u];
        #pragma unroll
        for (int t = 0; t < 8; ++t) acc[t] += g * w[(8 + u + t) & 15];
      }
      *(float4*)(&w[8])  = *(const float4*)(sp + swz(x0 + jj + 24));
      *(float4*)(&w[12]) = *(const float4*)(sp + swz(x0 + jj + 28));
    }
  }
  float* op = tmpH + (size_t)z * SLOT + (size_t)(ybase + r) * SW + x0;
  *(float4*)op       = make_float4(acc[0], acc[1], acc[2], acc[3]);
  *(float4*)(op + 4) = make_float4(acc[4], acc[5], acc[6], acc[7]);
}

__global__ __launch_bounds__(256) void fb_vpass(const RegionMeta* __restrict__ meta,
                             const float* __restrict__ g3all,
                             const float* __restrict__ tmpH,
                             float* __restrict__ blurred, int kk)
{
  __shared__ float g3s[256];
  int z = blockIdx.z;
  int reg = z * K_CNT + kk;
  int tid = threadIdx.x;
  RegionMeta m = meta[reg];
  g3s[tid] = g3all[(size_t)reg * 256 + tid];
  __syncthreads();
  if (m.skip) return;
  int ch = min(m.ye - m.ys, SH), cw = min(m.xe - m.xs, SW);
  int x = blockIdx.x * 256 + tid;
  if (x >= cw) return;
  int y0 = blockIdx.y * 16;
  if (y0 >= ch) return;
  int P = m.r * 3;
  int Lp = (m.L + 7) & ~7;
  const float* col = tmpH + (size_t)z * SLOT + x;
  int base = y0 - P;
  float w[32];
  #pragma unroll
  for (int s = 0; s < 32; ++s) {
    int rr = base + s;
    w[s] = (rr >= 0 && rr < ch) ? col[(size_t)rr * SW] : 0.f;
  }
  float acc[16];
  #pragma unroll
  for (int v = 0; v < 16; ++v) acc[v] = 0.f;
  for (int jj = 0; jj < Lp; jj += 32) {
    #define VPH(PH)                                                          \
    if (jj + (PH) < Lp) {                                                    \
      float ga[8];                                                           \
      *(float4*)(ga)     = *(const float4*)(g3s + jj + (PH));                \
      *(float4*)(ga + 4) = *(const float4*)(g3s + jj + (PH) + 4);            \
      _Pragma("unroll")                                                      \
      for (int u = 0; u < 8; ++u) {                                          \
        float g = ga[u];                                                     \
        _Pragma("unroll")                                                    \
        for (int v = 0; v < 16; ++v) acc[v] += g * w[((PH) + u + v) & 31];   \
      }                                                                      \
      int rb = base + jj + (PH) + 32;                                        \
      _Pragma("unroll")                                                      \
      for (int q = 0; q < 8; ++q) {                                          \
        int rr = rb + q;                                                     \
        w[((PH) + q) & 31] = (rr >= 0 && rr < ch) ? col[(size_t)rr * SW] : 0.f; \
      }                                                                      \
    }
    VPH(0) VPH(8) VPH(16) VPH(24)
    #undef VPH
  }
  float* op = blurred + (size_t)z * SLOT + (size_t)y0 * SW + x;
  #pragma unroll
  for (int v = 0; v < 16; ++v)
    if (y0 + v < ch) op[(size_t)v * SW] = acc[v];
}

__global__ void shift_kernel(const RegionMeta* __restrict__ meta,
                             const float* __restrict__ blurred,
                             float* __restrict__ sg, float* __restrict__ sl, int k)
{
  int i = blockIdx.y;
  RegionMeta m = meta[i * K_CNT + k];
  if (m.skip) return;
  int ch = min(m.ye - m.ys, SH), cw = min(m.xe - m.xs, SW);
  int idx = blockIdx.x * 256 + threadIdx.x;
  int x = idx % SW, y = idx / SW;
  if (y >= ch || x >= cw) return;
  float sy = (float)y - m.dyp;
  float sx = (float)x - m.dxp;
  float x0f = floorf(sx), y0f = floorf(sy);
  float wx = sx - x0f, wy = sy - y0f;
  int x0 = (int)x0f, y0 = (int)y0f;
  const float* bl = blurred + (size_t)i * SLOT;
  float v00 = (y0 >= 0 && y0 < ch && x0 >= 0 && x0 < cw) ? bl[y0 * SW + x0] : 0.f;
  float v01 = (y0 >= 0 && y0 < ch && x0 + 1 >= 0 && x0 + 1 < cw) ? bl[y0 * SW + x0 + 1] : 0.f;
  float v10 = (y0 + 1 >= 0 && y0 + 1 < ch && x0 >= 0 && x0 < cw) ? bl[(y0 + 1) * SW + x0] : 0.f;
  float v11 = (y0 + 1 >= 0 && y0 + 1 < ch && x0 + 1 >= 0 && x0 + 1 < cw) ? bl[(y0 + 1) * SW + x0 + 1] : 0.f;
  float v = (1.f - wy) * ((1.f - wx) * v00 + wx * v01) + wy * ((1.f - wx) * v10 + wx * v11);
  size_t o = ((size_t)i * IMG_H + (m.ys + y)) * IMG_W + (m.xs + x);
  sg[o] = v;
  if (v > 0.f) sl[o] = (float)(k + 1);
}

// ------------------------- launch -------------------------

extern "C" void kernel_launch(void* const* d_in, const int* in_sizes, int n_in,
                              void* d_out, int out_size, void* d_ws, size_t ws_size,
                              hipStream_t stream) {
  const float* alpha = (const float*)d_in[0];
  const float* sigp = (const float*)d_in[2];
  const float* tnhp = (const float*)d_in[3];
  const int* ta = (const int*)d_in[4];
  float* out = (float*)d_out;

  char* ws = (char*)d_ws;
  RegionMeta* meta = (RegionMeta*)ws;            // 1536 B
  int* bars = (int*)(ws + 2048);                 // 64 B
  float* g3 = (float*)(ws + 4096);               // 32 KiB
  float* sg = out;
  float* sl = out + (size_t)4 * IMG_H * IMG_W;

  const size_t slotBytes = (size_t)SLOT * 4;
  const size_t needPar = 65536 + 2 * 32 * slotBytes;   // ~42.4 MB
  float* tmpH = (float*)(ws + 65536);
  float* blurred = (float*)(ws + 65536 + 32 * slotBytes);

  int dev = 0;
  (void)hipGetDevice(&dev);
  int cus = 0;
  if (hipDeviceGetAttribute(&cus, hipDeviceAttributeMultiprocessorCount, dev) != hipSuccess || cus <= 0)
    cus = 256;
  int occ = 0;
  if (hipOccupancyMaxActiveBlocksPerMultiprocessor(&occ, mega_kernel, 256, 0) != hipSuccess)
    occ = 0;

  if (occ >= 1 && ws_size >= needPar) {
    int grid = occ * cus;
    (void)hipMemsetAsync(bars, 0, 64, stream);
    mega_kernel<<<grid, 256, 0, stream>>>(alpha, sigp, tnhp, ta, meta, g3,
                                          tmpH, blurred, sg, sl, bars);
  } else {
    // fallback: sequential over k, explicit write ordering (works for any ws >= 4 slots + tmp)
    float* tmpH4 = (float*)(ws + 65536);
    float* blurred4 = (float*)(ws + 65536 + 4 * slotBytes);
    meta_kernel<<<32, 64, 0, stream>>>(sigp, tnhp, ta, g3, meta);
    (void)hipMemsetAsync(d_out, 0, (size_t)out_size * sizeof(float), stream);
    const int blocksPerRegion = (SH * SW) / 256;
    for (int k = 0; k < K_CNT; ++k) {
      fb_hpass<<<dim3(RG_H, 4), 256, 0, stream>>>(alpha, meta, g3, tmpH4, k);
      fb_vpass<<<dim3(XTILES, YTILES, 4), 256, 0, stream>>>(meta, g3, tmpH4, blurred4, k);
      shift_kernel<<<dim3(blocksPerRegion, 4), 256, 0, stream>>>(meta, blurred4, sg, sl, k);
    }
  }
}

// Round 8
// 250.037 us; speedup vs baseline: 1.4269x; 1.4269x over previous
//
#include <hip/hip_runtime.h>
#include <math.h>

#define K_CNT 8
#define IMG_H 1024
#define IMG_W 1024
#define SW 608            // scratch row stride (floats); max region w = 606
#define SH 272            // scratch rows; max region h = 270
#define SLOT (SW * SH)    // floats per region slot

#define RG_H ((SH + 2) / 3)              // 91 3-row groups per region (mega hpass)
#define N_HITEMS (32 * RG_H)             // 2912
#define YTILES ((SH + 15) / 16)          // 17
#define XTILES ((SW + 255) / 256)        // 3
#define N_VITEMS (32 * YTILES * XTILES)  // 1632
#define N_CTILES ((4 * IMG_H * IMG_W) / 256)  // 16384

struct RegionMeta {
  int ys, ye, xs, xe;
  int skip, r, L;
  float dxp, dyp;
  int pad0, pad1, pad2;
};

// LDS bank swizzle: XOR f[8:6] into f[4:2]; keeps 16B blocks contiguous, spreads
// stride-32B window reads across all 8 bank-quads (else ~16-way conflict).
__device__ __forceinline__ int swz(int f) { return f ^ ((f >> 6) & 7) * 4; }

// ------------------------- mega-kernel phases -------------------------

__device__ __forceinline__ void gsync(int* bar)
{
  __syncthreads();
  if (threadIdx.x == 0) {
    __hip_atomic_fetch_add(bar, 1, __ATOMIC_RELEASE, __HIP_MEMORY_SCOPE_AGENT);
    while (__hip_atomic_load(bar, __ATOMIC_RELAXED, __HIP_MEMORY_SCOPE_AGENT) < (int)gridDim.x)
      __builtin_amdgcn_s_sleep(4);
    (void)__hip_atomic_load(bar, __ATOMIC_ACQUIRE, __HIP_MEMORY_SCOPE_AGENT);
  }
  __syncthreads();
}

__device__ void meta_phase(const float* __restrict__ sigp, const float* __restrict__ tnhp,
                           const int* __restrict__ ta, float* __restrict__ g3out,
                           RegionMeta* __restrict__ meta, float* smem)
{
  int bid = blockIdx.x;           // < 32: region i*K+k
  int k = bid & 7;
  int tid = threadIdx.x;
  float* gn = smem;               // 64
  float* g2 = smem + 64;          // 128
  int* bx = (int*)(smem + 192);   // 8

  if (tid < 8) bx[tid] = ta[bid * 8 + tid];
  __syncthreads();
  int ys0 = min(min(bx[1], bx[3]), min(bx[5], bx[7]));
  int ye0 = max(max(bx[1], bx[3]), max(bx[5], bx[7]));
  int xs0 = min(min(bx[0], bx[2]), min(bx[4], bx[6]));
  int xe0 = max(max(bx[0], bx[2]), max(bx[4], bx[6]));
  int h = ye0 - ys0, w = xe0 - xs0;

  // reference indexes flattened params by k only (batch-0 params for all i)
  float sig1 = sigp[k * 2 + 1];
  float t0 = tnhp[k * 2 + 0], t1 = tnhp[k * 2 + 1];

  float blur = ((sig1 + 1e-5f) * (float)h) * 0.5f;
  double kfac = 0.75 * sqrt(2.0 * M_PI);
  int ks = (int)floor((double)blur * kfac + 0.5);
  if (ks < 2) ks = 2;
  if ((ks & 1) == 0) ks += 1;
  int r_ = ks >> 1, P = r_ * 3, L = 3 * ks - 2;
  float dxp = (t0 * (float)h) * 0.2f;
  float dyp = (t1 * (float)h) * 0.2f;
  double eh = (double)P + fabs((double)dyp);
  double ew = (double)P + fabs((double)dxp);
  int ys = (int)fmax(fmin((double)ys0 - eh, (double)IMG_H), 0.0);
  int ye = (int)fmax(fmin((double)ye0 + eh, (double)IMG_H), 0.0);
  int xs = (int)fmax(fmin((double)xs0 - ew, (double)IMG_W), 0.0);
  int xe = (int)fmax(fmin((double)xe0 + ew, (double)IMG_W), 0.0);

  if (tid == 0) {
    RegionMeta m;
    m.ys = ys; m.ye = ye; m.xs = xs; m.xe = xe;
    m.skip = (h < 5 || w < 5) ? 1 : 0;
    m.r = r_; m.L = L; m.dxp = dxp; m.dyp = dyp;
    m.pad0 = m.pad1 = m.pad2 = 0;
    meta[bid] = m;
  }

  float mean = 0.5f * (float)(ks - 1);
  float inv = 1.0f / (2.0f * blur);
  if (tid < 64) {
    float gx = 0.f;
    if (tid < ks) { float d = ((float)tid - mean) * inv; gx = expf(-(d * d)); }
    float S = gx;
    #pragma unroll
    for (int off = 32; off > 0; off >>= 1) S += __shfl_xor(S, off);
    gn[tid] = (tid < ks) ? gx / S : 0.f;
  }
  __syncthreads();
  if (tid < 2 * ks - 1) {
    int a = tid;
    int blo = max(0, a - ks + 1), bhi = min(a, ks - 1);
    float s = 0.f;
    for (int b = blo; b <= bhi; ++b) s += gn[b] * gn[a - b];
    g2[a] = s;
  }
  __syncthreads();
  {
    int a = tid;
    float s = 0.f;
    if (a < L) {
      int blo = max(0, a - (2 * ks - 2)), bhi = min(a, ks - 1);
      for (int b = blo; b <= bhi; ++b) s += gn[b] * g2[a - b];
    }
    g3out[(size_t)bid * 256 + a] = s;   // zero-padded beyond L
  }
}

// hpass item: (region z, 3-row group). 256 threads = 3 rows x 76 chunks of 8 outputs.
__device__ void hpass_item(int item, const float* __restrict__ alpha,
                           const RegionMeta* __restrict__ meta,
                           const float* __restrict__ g3all,
                           float* __restrict__ tmpH, float* g3s, float* srow)
{
  int tid = threadIdx.x;
  int z = item / RG_H, rg = item - z * RG_H;
  RegionMeta m = meta[z];
  __syncthreads();                       // smem reuse guard
  g3s[tid] = g3all[(size_t)z * 256 + tid];
  int ch = min(m.ye - m.ys, SH), cw = min(m.xe - m.xs, SW);
  int ybase = rg * 3;
  int nrows = (!m.skip && ybase < ch) ? min(3, ch - ybase) : 0;
  int P = m.r * 3;
  int i = z >> 3;
  for (int s = tid; s < nrows * 208; s += 256) {
    int r = s / 208;
    int e = (s - r * 208) * 4;
    const float* row = alpha + ((size_t)i * IMG_H + (m.ys + ybase + r)) * IMG_W + m.xs;
    float4 v; float* vp = (float*)&v;
    #pragma unroll
    for (int u = 0; u < 4; ++u) { int c = e + u - P; vp[u] = (c >= 0 && c < cw) ? row[c] : 0.f; }
    *(float4*)(srow + r * 832 + swz(e)) = v;
  }
  __syncthreads();
  if (nrows) {
    int r = tid / 76, c = tid - (tid / 76) * 76;
    int x0 = 8 * c;
    if (r < nrows && x0 < cw) {
      const float* sp = srow + r * 832;
      float w[16], acc[8];
      #pragma unroll
      for (int q = 0; q < 4; ++q) *(float4*)(&w[4 * q]) = *(const float4*)(sp + swz(x0 + 4 * q));
      #pragma unroll
      for (int t = 0; t < 8; ++t) acc[t] = 0.f;
      int Lp = (m.L + 7) & ~7;
      for (int jj = 0; jj < Lp; jj += 16) {
        {
          float ga[8];
          *(float4*)(ga)     = *(const float4*)(g3s + jj);
          *(float4*)(ga + 4) = *(const float4*)(g3s + jj + 4);
          #pragma unroll
          for (int u = 0; u < 8; ++u) {
            float g = ga[u];
            #pragma unroll
            for (int t = 0; t < 8; ++t) acc[t] += g * w[(u + t) & 15];
          }
          *(float4*)(&w[0]) = *(const float4*)(sp + swz(x0 + jj + 16));
          *(float4*)(&w[4]) = *(const float4*)(sp + swz(x0 + jj + 20));
        }
        if (jj + 8 < Lp) {
          float ga[8];
          *(float4*)(ga)     = *(const float4*)(g3s + jj + 8);
          *(float4*)(ga + 4) = *(const float4*)(g3s + jj + 12);
          #pragma unroll
          for (int u = 0; u < 8; ++u) {
            float g = ga[u];
            #pragma unroll
            for (int t = 0; t < 8; ++t) acc[t] += g * w[(8 + u + t) & 15];
          }
          *(float4*)(&w[8])  = *(const float4*)(sp + swz(x0 + jj + 24));
          *(float4*)(&w[12]) = *(const float4*)(sp + swz(x0 + jj + 28));
        }
      }
      float* op = tmpH + (size_t)z * SLOT + (size_t)(ybase + r) * SW + x0;
      *(float4*)op       = make_float4(acc[0], acc[1], acc[2], acc[3]);
      *(float4*)(op + 4) = make_float4(acc[4], acc[5], acc[6], acc[7]);
    }
  }
}

// vpass item: (region z, 16-row tile, 256-col tile); 16 y-outputs per thread (ring w[32]).
__device__ void vpass_item(int item, const RegionMeta* __restrict__ meta,
                           const float* __restrict__ g3all,
                           const float* __restrict__ tmpH,
                           float* __restrict__ blurred, float* g3s)
{
  int tid = threadIdx.x;
  int z = item / (YTILES * XTILES);
  int rem = item - z * (YTILES * XTILES);
  int yg = rem / XTILES, xt = rem - (rem / XTILES) * XTILES;
  RegionMeta m = meta[z];
  __syncthreads();
  g3s[tid] = g3all[(size_t)z * 256 + tid];
  __syncthreads();
  if (m.skip) return;
  int ch = min(m.ye - m.ys, SH), cw = min(m.xe - m.xs, SW);
  int x = xt * 256 + tid;
  if (x >= cw) return;
  int y0 = yg * 16;
  if (y0 >= ch) return;
  int P = m.r * 3;
  int Lp = (m.L + 7) & ~7;
  const float* col = tmpH + (size_t)z * SLOT + x;
  int base = y0 - P;

  float w[32];
  if (base >= 0 && base + 31 < ch) {
    #pragma unroll
    for (int s = 0; s < 32; ++s) w[s] = col[(size_t)(base + s) * SW];
  } else {
    #pragma unroll
    for (int s = 0; s < 32; ++s) {
      int rr = base + s;
      w[s] = (rr >= 0 && rr < ch) ? col[(size_t)rr * SW] : 0.f;
    }
  }
  float acc[16];
  #pragma unroll
  for (int v = 0; v < 16; ++v) acc[v] = 0.f;

  for (int jj = 0; jj < Lp; jj += 32) {
    #define VPH(PH)                                                          \
    if (jj + (PH) < Lp) {                                                    \
      float ga[8];                                                           \
      *(float4*)(ga)     = *(const float4*)(g3s + jj + (PH));                \
      *(float4*)(ga + 4) = *(const float4*)(g3s + jj + (PH) + 4);            \
      _Pragma("unroll")                                                      \
      for (int u = 0; u < 8; ++u) {                                          \
        float g = ga[u];                                                     \
        _Pragma("unroll")                                                    \
        for (int v = 0; v < 16; ++v) acc[v] += g * w[((PH) + u + v) & 31];   \
      }                                                                      \
      int rb = base + jj + (PH) + 32;                                        \
      if (rb >= 0 && rb + 7 < ch) {                                          \
        _Pragma("unroll")                                                    \
        for (int q = 0; q < 8; ++q) w[((PH) + q) & 31] = col[(size_t)(rb + q) * SW]; \
      } else {                                                               \
        _Pragma("unroll")                                                    \
        for (int q = 0; q < 8; ++q) {                                        \
          int rr = rb + q;                                                   \
          w[((PH) + q) & 31] = (rr >= 0 && rr < ch) ? col[(size_t)rr * SW] : 0.f; \
        }                                                                    \
      }                                                                      \
    }
    VPH(0) VPH(8) VPH(16) VPH(24)
    #undef VPH
  }

  float* op = blurred + (size_t)z * SLOT + (size_t)y0 * SW + x;
  #pragma unroll
  for (int v = 0; v < 16; ++v)
    if (y0 + v < ch) op[(size_t)v * SW] = acc[v];
}

__device__ void composite_phase(const RegionMeta* __restrict__ meta,
                                const float* __restrict__ blurred,
                                float* __restrict__ sg, float* __restrict__ sl,
                                float* smem)
{
  RegionMeta* ms = (RegionMeta*)smem;
  {
    const int* src = (const int*)meta;
    int* dst = (int*)ms;
    for (int a = threadIdx.x; a < 32 * (int)(sizeof(RegionMeta) / 4); a += 256) dst[a] = src[a];
  }
  __syncthreads();
  for (int tile = blockIdx.x; tile < N_CTILES; tile += gridDim.x) {
    int idx = tile * 256 + (int)threadIdx.x;
    int x = idx & (IMG_W - 1);
    int y = (idx >> 10) & (IMG_H - 1);
    int i = idx >> 20;
    float sgv = 0.f, slv = 0.f;
    bool got = false;
    for (int k = K_CNT - 1; k >= 0; --k) {
      const RegionMeta& m = ms[i * K_CNT + k];
      if (m.skip) continue;
      int ch = min(m.ye - m.ys, SH), cw = min(m.xe - m.xs, SW);
      int ly = y - m.ys, lx = x - m.xs;
      if (ly < 0 || ly >= ch || lx < 0 || lx >= cw) continue;
      float sy = (float)ly - m.dyp;
      float sx = (float)lx - m.dxp;
      float x0f = floorf(sx), y0f = floorf(sy);
      float wx = sx - x0f, wy = sy - y0f;
      int x0 = (int)x0f, y0 = (int)y0f;
      const float* bl = blurred + (size_t)(i * K_CNT + k) * SLOT;
      float v00 = (y0 >= 0 && y0 < ch && x0 >= 0 && x0 < cw) ? bl[y0 * SW + x0] : 0.f;
      float v01 = (y0 >= 0 && y0 < ch && x0 + 1 >= 0 && x0 + 1 < cw) ? bl[y0 * SW + x0 + 1] : 0.f;
      float v10 = (y0 + 1 >= 0 && y0 + 1 < ch && x0 >= 0 && x0 < cw) ? bl[(y0 + 1) * SW + x0] : 0.f;
      float v11 = (y0 + 1 >= 0 && y0 + 1 < ch && x0 + 1 >= 0 && x0 + 1 < cw) ? bl[(y0 + 1) * SW + x0 + 1] : 0.f;
      float v = (1.f - wy) * ((1.f - wx) * v00 + wx * v01) + wy * ((1.f - wx) * v10 + wx * v11);
      if (!got) { sgv = v; got = true; }
      if (v > 0.f) { slv = (float)(k + 1); break; }
    }
    sg[idx] = sgv;
    sl[idx] = slv;
  }
}

__global__ __launch_bounds__(256, 2) void mega_kernel(
    const float* __restrict__ alpha, const float* __restrict__ sigp,
    const float* __restrict__ tnhp, const int* __restrict__ ta,
    RegionMeta* meta, float* g3all, float* tmpH, float* blurred,
    float* sg, float* sl, int* bars)
{
  __shared__ __align__(16) float g3s[256];
  __shared__ __align__(16) float smem[3 * 832];

  if (blockIdx.x < 32) meta_phase(sigp, tnhp, ta, g3all, meta, smem);
  gsync(&bars[0]);
  for (int it = blockIdx.x; it < N_HITEMS; it += gridDim.x)
    hpass_item(it, alpha, meta, g3all, tmpH, g3s, smem);
  gsync(&bars[1]);
  for (int it = blockIdx.x; it < N_VITEMS; it += gridDim.x)
    vpass_item(it, meta, g3all, tmpH, blurred, g3s);
  gsync(&bars[2]);
  composite_phase(meta, blurred, sg, sl, smem);
}

// ------------------------- fallback path (round-5 kernels) -------------------------

__global__ void meta_kernel(const float* __restrict__ sigp,
                            const float* __restrict__ tnhp,
                            const int* __restrict__ ta,
                            float* __restrict__ g3out,
                            RegionMeta* __restrict__ meta)
{
  int bid = blockIdx.x;
  int k = bid % K_CNT;
  int lane = threadIdx.x;
  __shared__ int bx[8];
  if (lane < 8) bx[lane] = ta[bid * 8 + lane];
  __syncthreads();
  int ys0 = min(min(bx[1], bx[3]), min(bx[5], bx[7]));
  int ye0 = max(max(bx[1], bx[3]), max(bx[5], bx[7]));
  int xs0 = min(min(bx[0], bx[2]), min(bx[4], bx[6]));
  int xe0 = max(max(bx[0], bx[2]), max(bx[4], bx[6]));
  int h = ye0 - ys0, w = xe0 - xs0;
  float sig1 = sigp[k * 2 + 1];
  float t0 = tnhp[k * 2 + 0], t1 = tnhp[k * 2 + 1];
  float blur = ((sig1 + 1e-5f) * (float)h) * 0.5f;
  double kfac = 0.75 * sqrt(2.0 * M_PI);
  int ks = (int)floor((double)blur * kfac + 0.5);
  if (ks < 2) ks = 2;
  if ((ks & 1) == 0) ks += 1;
  int r = ks >> 1, P = r * 3, L = 3 * ks - 2;
  float dxp = (t0 * (float)h) * 0.2f;
  float dyp = (t1 * (float)h) * 0.2f;
  double eh = (double)P + fabs((double)dyp);
  double ew = (double)P + fabs((double)dxp);
  int ys = (int)fmax(fmin((double)ys0 - eh, (double)IMG_H), 0.0);
  int ye = (int)fmax(fmin((double)ye0 + eh, (double)IMG_H), 0.0);
  int xs = (int)fmax(fmin((double)xs0 - ew, (double)IMG_W), 0.0);
  int xe = (int)fmax(fmin((double)xe0 + ew, (double)IMG_W), 0.0);
  int skip = (h < 5 || w < 5) ? 1 : 0;
  if (lane == 0) {
    RegionMeta m;
    m.ys = ys; m.ye = ye; m.xs = xs; m.xe = xe;
    m.skip = skip; m.r = r; m.L = L;
    m.dxp = dxp; m.dyp = dyp;
    m.pad0 = m.pad1 = m.pad2 = 0;
    meta[bid] = m;
  }
  float mean = 0.5f * (float)(ks - 1);
  float inv = 1.0f / (2.0f * blur);
  float gx = 0.f;
  if (lane < ks) { float d = ((float)lane - mean) * inv; gx = expf(-(d * d)); }
  float S = gx;
  #pragma unroll
  for (int off = 32; off > 0; off >>= 1) S += __shfl_xor(S, off);
  __shared__ float gn[64];
  gn[lane] = (lane < ks) ? gx / S : 0.f;
  __syncthreads();
  __shared__ float g2[128];
  for (int a = lane; a < 2 * ks - 1; a += 64) {
    int blo = max(0, a - ks + 1), bhi = min(a, ks - 1);
    float s = 0.f;
    for (int b = blo; b <= bhi; ++b) s += gn[b] * gn[a - b];
    g2[a] = s;
  }
  __syncthreads();
  float* g3 = g3out + (size_t)bid * 256;
  for (int a = lane; a < 256; a += 64) {
    float s = 0.f;
    if (a < L) {
      int blo = max(0, a - (2 * ks - 2)), bhi = min(a, ks - 1);
      for (int b = blo; b <= bhi; ++b) s += gn[b] * g2[a - b];
    }
    g3[a] = s;
  }
}

__global__ __launch_bounds__(256) void fb_hpass(const float* __restrict__ alpha,
                             const RegionMeta* __restrict__ meta,
                             const float* __restrict__ g3all,
                             float* __restrict__ tmpH, int kk)
{
  __shared__ __align__(16) float g3s[256];
  __shared__ __align__(16) float srow[3 * 832];
  int z = blockIdx.y;
  int reg = z * K_CNT + kk;
  int tid = threadIdx.x;
  RegionMeta m = meta[reg];
  g3s[tid] = g3all[(size_t)reg * 256 + tid];
  int ch = min(m.ye - m.ys, SH), cw = min(m.xe - m.xs, SW);
  int ybase = blockIdx.x * 3;
  int nrows = (!m.skip && ybase < ch) ? min(3, ch - ybase) : 0;
  int P = m.r * 3;
  for (int s = tid; s < nrows * 208; s += 256) {
    int r = s / 208;
    int e = (s - r * 208) * 4;
    const float* row = alpha + ((size_t)z * IMG_H + (m.ys + ybase + r)) * IMG_W + m.xs;
    float4 v; float* vp = (float*)&v;
    #pragma unroll
    for (int u = 0; u < 4; ++u) { int c = e + u - P; vp[u] = (c >= 0 && c < cw) ? row[c] : 0.f; }
    *(float4*)(srow + r * 832 + swz(e)) = v;
  }
  __syncthreads();
  if (!nrows) return;
  int r = tid / 76, c = tid - (tid / 76) * 76;
  int x0 = 8 * c;
  if (r >= nrows || x0 >= cw) return;
  const float* sp = srow + r * 832;
  float w[16], acc[8];
  #pragma unroll
  for (int q = 0; q < 4; ++q) *(float4*)(&w[4 * q]) = *(const float4*)(sp + swz(x0 + 4 * q));
  #pragma unroll
  for (int t = 0; t < 8; ++t) acc[t] = 0.f;
  int Lp = (m.L + 7) & ~7;
  for (int jj = 0; jj < Lp; jj += 16) {
    {
      float ga[8];
      *(float4*)(ga) = *(const float4*)(g3s + jj);
      *(float4*)(ga + 4) = *(const float4*)(g3s + jj + 4);
      #pragma unroll
      for (int u = 0; u < 8; ++u) {
        float g = ga[u];
        #pragma unroll
        for (int t = 0; t < 8; ++t) acc[t] += g * w[(u + t) & 15];
      }
      *(float4*)(&w[0]) = *(const float4*)(sp + swz(x0 + jj + 16));
      *(float4*)(&w[4]) = *(const float4*)(sp + swz(x0 + jj + 20));
    }
    if (jj + 8 < Lp) {
      float ga[8];
      *(float4*)(ga) = *(const float4*)(g3s + jj + 8);
      *(float4*)(ga + 4) = *(const float4*)(g3s + jj + 12);
      #pragma unroll
      for (int u = 0; u < 8; ++u) {
        float g = ga[u];
        #pragma unroll
        for (int t = 0; t < 8; ++t) acc[t] += g * w[(8 + u + t) & 15];
      }
      *(float4*)(&w[8])  = *(const float4*)(sp + swz(x0 + jj + 24));
      *(float4*)(&w[12]) = *(const float4*)(sp + swz(x0 + jj + 28));
    }
  }
  float* op = tmpH + (size_t)z * SLOT + (size_t)(ybase + r) * SW + x0;
  *(float4*)op       = make_float4(acc[0], acc[1], acc[2], acc[3]);
  *(float4*)(op + 4) = make_float4(acc[4], acc[5], acc[6], acc[7]);
}

__global__ __launch_bounds__(256) void fb_vpass(const RegionMeta* __restrict__ meta,
                             const float* __restrict__ g3all,
                             const float* __restrict__ tmpH,
                             float* __restrict__ blurred, int kk)
{
  __shared__ float g3s[256];
  int z = blockIdx.z;
  int reg = z * K_CNT + kk;
  int tid = threadIdx.x;
  RegionMeta m = meta[reg];
  g3s[tid] = g3all[(size_t)reg * 256 + tid];
  __syncthreads();
  if (m.skip) return;
  int ch = min(m.ye - m.ys, SH), cw = min(m.xe - m.xs, SW);
  int x = blockIdx.x * 256 + tid;
  if (x >= cw) return;
  int y0 = blockIdx.y * 16;
  if (y0 >= ch) return;
  int P = m.r * 3;
  int Lp = (m.L + 7) & ~7;
  const float* col = tmpH + (size_t)z * SLOT + x;
  int base = y0 - P;
  float w[32];
  #pragma unroll
  for (int s = 0; s < 32; ++s) {
    int rr = base + s;
    w[s] = (rr >= 0 && rr < ch) ? col[(size_t)rr * SW] : 0.f;
  }
  float acc[16];
  #pragma unroll
  for (int v = 0; v < 16; ++v) acc[v] = 0.f;
  for (int jj = 0; jj < Lp; jj += 32) {
    #define VPH(PH)                                                          \
    if (jj + (PH) < Lp) {                                                    \
      float ga[8];                                                           \
      *(float4*)(ga)     = *(const float4*)(g3s + jj + (PH));                \
      *(float4*)(ga + 4) = *(const float4*)(g3s + jj + (PH) + 4);            \
      _Pragma("unroll")                                                      \
      for (int u = 0; u < 8; ++u) {                                          \
        float g = ga[u];                                                     \
        _Pragma("unroll")                                                    \
        for (int v = 0; v < 16; ++v) acc[v] += g * w[((PH) + u + v) & 31];   \
      }                                                                      \
      int rb = base + jj + (PH) + 32;                                        \
      _Pragma("unroll")                                                      \
      for (int q = 0; q < 8; ++q) {                                          \
        int rr = rb + q;                                                     \
        w[((PH) + q) & 31] = (rr >= 0 && rr < ch) ? col[(size_t)rr * SW] : 0.f; \
      }                                                                      \
    }
    VPH(0) VPH(8) VPH(16) VPH(24)
    #undef VPH
  }
  float* op = blurred + (size_t)z * SLOT + (size_t)y0 * SW + x;
  #pragma unroll
  for (int v = 0; v < 16; ++v)
    if (y0 + v < ch) op[(size_t)v * SW] = acc[v];
}

__global__ void shift_kernel(const RegionMeta* __restrict__ meta,
                             const float* __restrict__ blurred,
                             float* __restrict__ sg, float* __restrict__ sl, int k)
{
  int i = blockIdx.y;
  RegionMeta m = meta[i * K_CNT + k];
  if (m.skip) return;
  int ch = min(m.ye - m.ys, SH), cw = min(m.xe - m.xs, SW);
  int idx = blockIdx.x * 256 + threadIdx.x;
  int x = idx % SW, y = idx / SW;
  if (y >= ch || x >= cw) return;
  float sy = (float)y - m.dyp;
  float sx = (float)x - m.dxp;
  float x0f = floorf(sx), y0f = floorf(sy);
  float wx = sx - x0f, wy = sy - y0f;
  int x0 = (int)x0f, y0 = (int)y0f;
  const float* bl = blurred + (size_t)i * SLOT;
  float v00 = (y0 >= 0 && y0 < ch && x0 >= 0 && x0 < cw) ? bl[y0 * SW + x0] : 0.f;
  float v01 = (y0 >= 0 && y0 < ch && x0 + 1 >= 0 && x0 + 1 < cw) ? bl[y0 * SW + x0 + 1] : 0.f;
  float v10 = (y0 + 1 >= 0 && y0 + 1 < ch && x0 >= 0 && x0 < cw) ? bl[(y0 + 1) * SW + x0] : 0.f;
  float v11 = (y0 + 1 >= 0 && y0 + 1 < ch && x0 + 1 >= 0 && x0 + 1 < cw) ? bl[(y0 + 1) * SW + x0 + 1] : 0.f;
  float v = (1.f - wy) * ((1.f - wx) * v00 + wx * v01) + wy * ((1.f - wx) * v10 + wx * v11);
  size_t o = ((size_t)i * IMG_H + (m.ys + y)) * IMG_W + (m.xs + x);
  sg[o] = v;
  if (v > 0.f) sl[o] = (float)(k + 1);
}

// ------------------------- launch -------------------------

extern "C" void kernel_launch(void* const* d_in, const int* in_sizes, int n_in,
                              void* d_out, int out_size, void* d_ws, size_t ws_size,
                              hipStream_t stream) {
  const float* alpha = (const float*)d_in[0];
  const float* sigp = (const float*)d_in[2];
  const float* tnhp = (const float*)d_in[3];
  const int* ta = (const int*)d_in[4];
  float* out = (float*)d_out;

  char* ws = (char*)d_ws;
  RegionMeta* meta = (RegionMeta*)ws;            // 1536 B
  int* bars = (int*)(ws + 2048);                 // 64 B
  float* g3 = (float*)(ws + 4096);               // 32 KiB
  float* sg = out;
  float* sl = out + (size_t)4 * IMG_H * IMG_W;

  const size_t slotBytes = (size_t)SLOT * 4;
  const size_t needPar = 65536 + 2 * 32 * slotBytes;   // ~42.4 MB
  float* tmpH = (float*)(ws + 65536);
  float* blurred = (float*)(ws + 65536 + 32 * slotBytes);

  int dev = 0;
  (void)hipGetDevice(&dev);
  int cus = 0;
  if (hipDeviceGetAttribute(&cus, hipDeviceAttributeMultiprocessorCount, dev) != hipSuccess || cus <= 0)
    cus = 256;
  int occ = 0;
  if (hipOccupancyMaxActiveBlocksPerMultiprocessor(&occ, mega_kernel, 256, 0) != hipSuccess)
    occ = 0;

  if (occ >= 1 && ws_size >= needPar) {
    int grid = occ * cus;
    (void)hipMemsetAsync(bars, 0, 64, stream);
    mega_kernel<<<grid, 256, 0, stream>>>(alpha, sigp, tnhp, ta, meta, g3,
                                          tmpH, blurred, sg, sl, bars);
  } else {
    // fallback: sequential over k, explicit write ordering (works for any ws >= 4 slots + tmp)
    float* tmpH4 = (float*)(ws + 65536);
    float* blurred4 = (float*)(ws + 65536 + 4 * slotBytes);
    meta_kernel<<<32, 64, 0, stream>>>(sigp, tnhp, ta, g3, meta);
    (void)hipMemsetAsync(d_out, 0, (size_t)out_size * sizeof(float), stream);
    const int blocksPerRegion = (SH * SW) / 256;
    for (int k = 0; k < K_CNT; ++k) {
      fb_hpass<<<dim3(RG_H, 4), 256, 0, stream>>>(alpha, meta, g3, tmpH4, k);
      fb_vpass<<<dim3(XTILES, YTILES, 4), 256, 0, stream>>>(meta, g3, tmpH4, blurred4, k);
      shift_kernel<<<dim3(blocksPerRegion, 4), 256, 0, stream>>>(meta, blurred4, sg, sl, k);
    }
  }
}

// Round 9
// 94.346 us; speedup vs baseline: 3.7816x; 2.6502x over previous
//
#include <hip/hip_runtime.h>
#include <math.h>

#define K_CNT 8
#define IMG_H 1024
#define IMG_W 1024
#define SW 608            // scratch row stride (floats); max region w = 606
#define SH 272            // scratch rows; max region h = 270
#define SLOT (SW * SH)    // floats per region slot

#define RG_H ((SH + 2) / 3)              // 91 3-row groups per region
#define YTILES ((SH + 15) / 16)          // 17
#define XTILES ((SW + 255) / 256)        // 3

struct RegionMeta {
  int ys, ye, xs, xe;
  int skip, r, L;
  float dxp, dyp;
  int pad0, pad1, pad2;
};

// LDS bank swizzle: XOR f[8:6] into f[4:2]; keeps float4 blocks contiguous,
// spreads the 8-float-stride b128 window reads across bank quads
// (unswizzled: lanes with equal c%4 share one quad -> 16-way conflict).
__device__ __forceinline__ int swz(int f) { return f ^ ((f >> 6) & 7) * 4; }

// One block (64 threads) per (i,k) region: rect, offsets, and the 1D kernel
// gn3 = gn*gn*gn (separable equivalent of 3x 2D gauss conv).
__global__ void meta_kernel(const float* __restrict__ sigp,
                            const float* __restrict__ tnhp,
                            const int* __restrict__ ta,
                            float* __restrict__ g3out,
                            RegionMeta* __restrict__ meta)
{
  int bid = blockIdx.x;          // i*K + k
  int k = bid % K_CNT;
  int lane = threadIdx.x;

  __shared__ int bx[8];
  if (lane < 8) bx[lane] = ta[bid * 8 + lane];
  __syncthreads();
  int ys0 = min(min(bx[1], bx[3]), min(bx[5], bx[7]));
  int ye0 = max(max(bx[1], bx[3]), max(bx[5], bx[7]));
  int xs0 = min(min(bx[0], bx[2]), min(bx[4], bx[6]));
  int xe0 = max(max(bx[0], bx[2]), max(bx[4], bx[6]));
  int h = ye0 - ys0, w = xe0 - xs0;

  // reference indexes flattened params by k only (batch-0 params for all i)
  float sig1 = sigp[k * 2 + 1];
  float t0 = tnhp[k * 2 + 0], t1 = tnhp[k * 2 + 1];

  float blur = ((sig1 + 1e-5f) * (float)h) * 0.5f;      // f32 like jnp
  double kfac = 0.75 * sqrt(2.0 * M_PI);                // exact Python f64 path
  int ks = (int)floor((double)blur * kfac + 0.5);
  if (ks < 2) ks = 2;
  if ((ks & 1) == 0) ks += 1;
  int r = ks >> 1, P = r * 3, L = 3 * ks - 2;
  float dxp = (t0 * (float)h) * 0.2f;
  float dyp = (t1 * (float)h) * 0.2f;
  double eh = (double)P + fabs((double)dyp);
  double ew = (double)P + fabs((double)dxp);
  int ys = (int)fmax(fmin((double)ys0 - eh, (double)IMG_H), 0.0);
  int ye = (int)fmax(fmin((double)ye0 + eh, (double)IMG_H), 0.0);
  int xs = (int)fmax(fmin((double)xs0 - ew, (double)IMG_W), 0.0);
  int xe = (int)fmax(fmin((double)xe0 + ew, (double)IMG_W), 0.0);
  int skip = (h < 5 || w < 5) ? 1 : 0;

  if (lane == 0) {
    RegionMeta m;
    m.ys = ys; m.ye = ye; m.xs = xs; m.xe = xe;
    m.skip = skip; m.r = r; m.L = L;
    m.dxp = dxp; m.dyp = dyp;
    m.pad0 = m.pad1 = m.pad2 = 0;
    meta[bid] = m;
  }

  float mean = 0.5f * (float)(ks - 1);
  float inv = 1.0f / (2.0f * blur);
  float gx = 0.f;
  if (lane < ks) { float d = ((float)lane - mean) * inv; gx = expf(-(d * d)); }
  float S = gx;
  #pragma unroll
  for (int off = 32; off > 0; off >>= 1) S += __shfl_xor(S, off);
  __shared__ float gn[64];
  gn[lane] = (lane < ks) ? gx / S : 0.f;
  __syncthreads();

  __shared__ float g2[128];
  for (int a = lane; a < 2 * ks - 1; a += 64) {
    int blo = max(0, a - ks + 1), bhi = min(a, ks - 1);
    float s = 0.f;
    for (int b = blo; b <= bhi; ++b) s += gn[b] * gn[a - b];
    g2[a] = s;
  }
  __syncthreads();

  float* g3 = g3out + (size_t)bid * 256;
  for (int a = lane; a < 256; a += 64) {
    float s = 0.f;
    if (a < L) {
      int blo = max(0, a - (2 * ks - 2)), bhi = min(a, ks - 1);
      for (int b = blo; b <= bhi; ++b) s += gn[b] * g2[a - b];
    }
    g3[a] = s;   // zero-padded beyond L (rolling loops rely on this)
  }
}

// Horizontal pass: block = (region, 3-row group); 256 threads = 3 rows x 76
// chunks of 8 outputs; swizzled LDS row -> conflict-free b128 window reads.
// kk >= 0: fallback (region = z*K+kk, slot z in 0..3). kk == -1: region = z.
__global__ __launch_bounds__(256) void hpass_kernel(const float* __restrict__ alpha,
                             const RegionMeta* __restrict__ meta,
                             const float* __restrict__ g3all,
                             float* __restrict__ tmpH, int kk)
{
  __shared__ __align__(16) float g3s[256];
  __shared__ __align__(16) float srow[3 * 832];
  int z = blockIdx.y;
  int reg = (kk >= 0) ? z * K_CNT + kk : z;
  int i   = (kk >= 0) ? z : z / K_CNT;
  int tid = threadIdx.x;
  RegionMeta m = meta[reg];
  g3s[tid] = g3all[(size_t)reg * 256 + tid];
  int ch = min(m.ye - m.ys, SH), cw = min(m.xe - m.xs, SW);
  int ybase = blockIdx.x * 3;
  int nrows = (!m.skip && ybase < ch) ? min(3, ch - ybase) : 0;
  int P = m.r * 3;
  for (int s = tid; s < nrows * 208; s += 256) {
    int r = s / 208;
    int e = (s - r * 208) * 4;
    const float* row = alpha + ((size_t)i * IMG_H + (m.ys + ybase + r)) * IMG_W + m.xs;
    float4 v; float* vp = (float*)&v;
    #pragma unroll
    for (int u = 0; u < 4; ++u) { int c = e + u - P; vp[u] = (c >= 0 && c < cw) ? row[c] : 0.f; }
    *(float4*)(srow + r * 832 + swz(e)) = v;
  }
  __syncthreads();
  if (!nrows) return;
  int r = tid / 76, c = tid - (tid / 76) * 76;
  int x0 = 8 * c;
  if (r >= nrows || x0 >= cw) return;
  const float* sp = srow + r * 832;
  float w[16], acc[8];
  #pragma unroll
  for (int q = 0; q < 4; ++q) *(float4*)(&w[4 * q]) = *(const float4*)(sp + swz(x0 + 4 * q));
  #pragma unroll
  for (int t = 0; t < 8; ++t) acc[t] = 0.f;
  int Lp = (m.L + 7) & ~7;
  for (int jj = 0; jj < Lp; jj += 16) {
    {
      float ga[8];
      *(float4*)(ga)     = *(const float4*)(g3s + jj);
      *(float4*)(ga + 4) = *(const float4*)(g3s + jj + 4);
      #pragma unroll
      for (int u = 0; u < 8; ++u) {
        float g = ga[u];
        #pragma unroll
        for (int t = 0; t < 8; ++t) acc[t] += g * w[(u + t) & 15];
      }
      *(float4*)(&w[0]) = *(const float4*)(sp + swz(x0 + jj + 16));
      *(float4*)(&w[4]) = *(const float4*)(sp + swz(x0 + jj + 20));
    }
    if (jj + 8 < Lp) {
      float ga[8];
      *(float4*)(ga)     = *(const float4*)(g3s + jj + 8);
      *(float4*)(ga + 4) = *(const float4*)(g3s + jj + 12);
      #pragma unroll
      for (int u = 0; u < 8; ++u) {
        float g = ga[u];
        #pragma unroll
        for (int t = 0; t < 8; ++t) acc[t] += g * w[(8 + u + t) & 15];
      }
      *(float4*)(&w[8])  = *(const float4*)(sp + swz(x0 + jj + 24));
      *(float4*)(&w[12]) = *(const float4*)(sp + swz(x0 + jj + 28));
    }
  }
  float* op = tmpH + (size_t)z * SLOT + (size_t)(ybase + r) * SW + x0;
  *(float4*)op       = make_float4(acc[0], acc[1], acc[2], acc[3]);
  *(float4*)(op + 4) = make_float4(acc[4], acc[5], acc[6], acc[7]);
}

// Vertical pass: 16 consecutive y-outputs per thread via 32-float register
// ring on the global column; guard-free loads except at y-boundaries.
__global__ __launch_bounds__(256) void vpass_kernel(const RegionMeta* __restrict__ meta,
                             const float* __restrict__ g3all,
                             const float* __restrict__ tmpH,
                             float* __restrict__ blurred, int kk)
{
  __shared__ float g3s[256];
  int z = blockIdx.z;
  int reg = (kk >= 0) ? z * K_CNT + kk : z;
  int tid = threadIdx.x;
  RegionMeta m = meta[reg];
  g3s[tid] = g3all[(size_t)reg * 256 + tid];
  __syncthreads();
  if (m.skip) return;
  int ch = min(m.ye - m.ys, SH), cw = min(m.xe - m.xs, SW);
  int x = blockIdx.x * 256 + tid;
  if (x >= cw) return;
  int y0 = blockIdx.y * 16;
  if (y0 >= ch) return;
  int P = m.r * 3;
  int Lp = (m.L + 7) & ~7;
  const float* col = tmpH + (size_t)z * SLOT + x;
  int base = y0 - P;

  float w[32];
  if (base >= 0 && base + 31 < ch) {
    #pragma unroll
    for (int s = 0; s < 32; ++s) w[s] = col[(size_t)(base + s) * SW];
  } else {
    #pragma unroll
    for (int s = 0; s < 32; ++s) {
      int rr = base + s;
      w[s] = (rr >= 0 && rr < ch) ? col[(size_t)rr * SW] : 0.f;
    }
  }
  float acc[16];
  #pragma unroll
  for (int v = 0; v < 16; ++v) acc[v] = 0.f;

  for (int jj = 0; jj < Lp; jj += 32) {
    #define VPH(PH)                                                          \
    if (jj + (PH) < Lp) {                                                    \
      float ga[8];                                                           \
      *(float4*)(ga)     = *(const float4*)(g3s + jj + (PH));                \
      *(float4*)(ga + 4) = *(const float4*)(g3s + jj + (PH) + 4);            \
      _Pragma("unroll")                                                      \
      for (int u = 0; u < 8; ++u) {                                          \
        float g = ga[u];                                                     \
        _Pragma("unroll")                                                    \
        for (int v = 0; v < 16; ++v) acc[v] += g * w[((PH) + u + v) & 31];   \
      }                                                                      \
      int rb = base + jj + (PH) + 32;                                        \
      if (rb >= 0 && rb + 7 < ch) {                                          \
        _Pragma("unroll")                                                    \
        for (int q = 0; q < 8; ++q) w[((PH) + q) & 31] = col[(size_t)(rb + q) * SW]; \
      } else {                                                               \
        _Pragma("unroll")                                                    \
        for (int q = 0; q < 8; ++q) {                                        \
          int rr = rb + q;                                                   \
          w[((PH) + q) & 31] = (rr >= 0 && rr < ch) ? col[(size_t)rr * SW] : 0.f; \
        }                                                                    \
      }                                                                      \
    }
    VPH(0) VPH(8) VPH(16) VPH(24)
    #undef VPH
  }

  float* op = blurred + (size_t)z * SLOT + (size_t)y0 * SW + x;
  #pragma unroll
  for (int v = 0; v < 16; ++v)
    if (y0 + v < ch) op[(size_t)v * SW] = acc[v];
}

// Parallel path: resolve ascending-k overwrite semantics by descending-k scan.
__global__ void composite_kernel(const RegionMeta* __restrict__ meta,
                                 const float* __restrict__ blurred,
                                 float* __restrict__ sg, float* __restrict__ sl)
{
  __shared__ RegionMeta ms[32];
  {
    const int* src = (const int*)meta;
    int* dst = (int*)ms;
    for (int a = threadIdx.x; a < 32 * (int)(sizeof(RegionMeta) / 4); a += 256) dst[a] = src[a];
  }
  __syncthreads();
  int idx = blockIdx.x * 256 + threadIdx.x;
  int x = idx & (IMG_W - 1);
  int y = (idx >> 10) & (IMG_H - 1);
  int i = idx >> 20;
  float sgv = 0.f, slv = 0.f;
  bool got = false;
  for (int k = K_CNT - 1; k >= 0; --k) {
    const RegionMeta& m = ms[i * K_CNT + k];
    if (m.skip) continue;
    int ch = min(m.ye - m.ys, SH), cw = min(m.xe - m.xs, SW);
    int ly = y - m.ys, lx = x - m.xs;
    if (ly < 0 || ly >= ch || lx < 0 || lx >= cw) continue;
    float sy = (float)ly - m.dyp;
    float sx = (float)lx - m.dxp;
    float x0f = floorf(sx), y0f = floorf(sy);
    float wx = sx - x0f, wy = sy - y0f;
    int x0 = (int)x0f, y0 = (int)y0f;
    const float* bl = blurred + (size_t)(i * K_CNT + k) * SLOT;
    float v00 = (y0 >= 0 && y0 < ch && x0 >= 0 && x0 < cw) ? bl[y0 * SW + x0] : 0.f;
    float v01 = (y0 >= 0 && y0 < ch && x0 + 1 >= 0 && x0 + 1 < cw) ? bl[y0 * SW + x0 + 1] : 0.f;
    float v10 = (y0 + 1 >= 0 && y0 + 1 < ch && x0 >= 0 && x0 < cw) ? bl[(y0 + 1) * SW + x0] : 0.f;
    float v11 = (y0 + 1 >= 0 && y0 + 1 < ch && x0 + 1 >= 0 && x0 + 1 < cw) ? bl[(y0 + 1) * SW + x0 + 1] : 0.f;
    float v = (1.f - wy) * ((1.f - wx) * v00 + wx * v01) + wy * ((1.f - wx) * v10 + wx * v11);
    if (!got) { sgv = v; got = true; }
    if (v > 0.f) { slv = (float)(k + 1); break; }
  }
  sg[idx] = sgv;
  sl[idx] = slv;
}

// Fallback-path bilinear translate + write (ascending-k launches give ordering)
__global__ void shift_kernel(const RegionMeta* __restrict__ meta,
                             const float* __restrict__ blurred,
                             float* __restrict__ sg, float* __restrict__ sl, int k)
{
  int i = blockIdx.y;
  RegionMeta m = meta[i * K_CNT + k];
  if (m.skip) return;
  int ch = min(m.ye - m.ys, SH), cw = min(m.xe - m.xs, SW);
  int idx = blockIdx.x * 256 + threadIdx.x;
  int x = idx % SW, y = idx / SW;
  if (y >= ch || x >= cw) return;
  float sy = (float)y - m.dyp;
  float sx = (float)x - m.dxp;
  float x0f = floorf(sx), y0f = floorf(sy);
  float wx = sx - x0f, wy = sy - y0f;
  int x0 = (int)x0f, y0 = (int)y0f;
  const float* bl = blurred + (size_t)i * SLOT;
  float v00 = (y0 >= 0 && y0 < ch && x0 >= 0 && x0 < cw) ? bl[y0 * SW + x0] : 0.f;
  float v01 = (y0 >= 0 && y0 < ch && x0 + 1 >= 0 && x0 + 1 < cw) ? bl[y0 * SW + x0 + 1] : 0.f;
  float v10 = (y0 + 1 >= 0 && y0 + 1 < ch && x0 >= 0 && x0 < cw) ? bl[(y0 + 1) * SW + x0] : 0.f;
  float v11 = (y0 + 1 >= 0 && y0 + 1 < ch && x0 + 1 >= 0 && x0 + 1 < cw) ? bl[(y0 + 1) * SW + x0 + 1] : 0.f;
  float v = (1.f - wy) * ((1.f - wx) * v00 + wx * v01) + wy * ((1.f - wx) * v10 + wx * v11);
  size_t o = ((size_t)i * IMG_H + (m.ys + y)) * IMG_W + (m.xs + x);
  sg[o] = v;
  if (v > 0.f) sl[o] = (float)(k + 1);
}

extern "C" void kernel_launch(void* const* d_in, const int* in_sizes, int n_in,
                              void* d_out, int out_size, void* d_ws, size_t ws_size,
                              hipStream_t stream) {
  const float* alpha = (const float*)d_in[0];
  // d_in[1] (font_size_pred) is unused by the reference
  const float* sigp = (const float*)d_in[2];
  const float* tnhp = (const float*)d_in[3];
  const int* ta = (const int*)d_in[4];
  float* out = (float*)d_out;

  char* ws = (char*)d_ws;
  RegionMeta* meta = (RegionMeta*)ws;
  float* g3 = (float*)(ws + 4096);

  float* sg = out;
  float* sl = out + (size_t)4 * IMG_H * IMG_W;

  const size_t slotBytes = (size_t)SLOT * 4;
  const size_t needPar = 65536 + 2 * 32 * slotBytes;   // ~42.4 MB

  meta_kernel<<<32, 64, 0, stream>>>(sigp, tnhp, ta, g3, meta);

  if (ws_size >= needPar) {
    // fully parallel across all 32 regions; ordering resolved in composite
    float* tmpH = (float*)(ws + 65536);
    float* blurred = (float*)(ws + 65536 + 32 * slotBytes);
    hpass_kernel<<<dim3(RG_H, 32), 256, 0, stream>>>(alpha, meta, g3, tmpH, -1);
    vpass_kernel<<<dim3(XTILES, YTILES, 32), 256, 0, stream>>>(meta, g3, tmpH, blurred, -1);
    composite_kernel<<<(4 * IMG_H * IMG_W) / 256, 256, 0, stream>>>(meta, blurred, sg, sl);
  } else {
    // fallback: sequential over k (4 regions in parallel), explicit write ordering
    float* tmpH = (float*)(ws + 65536);
    float* blurred = (float*)(ws + 65536 + 4 * slotBytes);
    (void)hipMemsetAsync(d_out, 0, (size_t)out_size * sizeof(float), stream);
    const int blocksPerRegion = (SH * SW) / 256;
    for (int k = 0; k < K_CNT; ++k) {
      hpass_kernel<<<dim3(RG_H, 4), 256, 0, stream>>>(alpha, meta, g3, tmpH, k);
      vpass_kernel<<<dim3(XTILES, YTILES, 4), 256, 0, stream>>>(meta, g3, tmpH, blurred, k);
      shift_kernel<<<dim3(blocksPerRegion, 4), 256, 0, stream>>>(meta, blurred, sg, sl, k);
    }
  }
}

// Round 10
// 88.435 us; speedup vs baseline: 4.0344x; 1.0668x over previous
//
#include <hip/hip_runtime.h>
#include <math.h>

#define K_CNT 8
#define IMG_H 1024
#define IMG_W 1024
#define SW 608            // scratch row stride (floats); max region w = 606
#define SH 272            // scratch rows; max region h = 270
#define SLOT (SW * SH)    // floats per region slot

#define RG_H ((SH + 2) / 3)              // 91 3-row groups per region
#define YTILES ((SH + 15) / 16)          // 17
#define XTILES ((SW + 255) / 256)        // 3

struct RegionMeta {
  int ys, ye, xs, xe;
  int skip, r, L;
  float dxp, dyp;
  int pad0, pad1, pad2;
};

// LDS bank swizzle: XOR f[8:6] into f[4:2]; keeps float4 blocks contiguous,
// spreads the 8-float-stride b128 window reads across bank quads.
__device__ __forceinline__ int swz(int f) { return f ^ ((f >> 6) & 7) * 4; }

// One block (64 threads) per (i,k) region: rect, offsets, and the 1D kernel
// gn3 = gn*gn*gn (separable equivalent of 3x 2D gauss conv).
__global__ void meta_kernel(const float* __restrict__ sigp,
                            const float* __restrict__ tnhp,
                            const int* __restrict__ ta,
                            float* __restrict__ g3out,
                            RegionMeta* __restrict__ meta)
{
  int bid = blockIdx.x;          // i*K + k
  int k = bid % K_CNT;
  int lane = threadIdx.x;

  __shared__ int bx[8];
  if (lane < 8) bx[lane] = ta[bid * 8 + lane];
  __syncthreads();
  int ys0 = min(min(bx[1], bx[3]), min(bx[5], bx[7]));
  int ye0 = max(max(bx[1], bx[3]), max(bx[5], bx[7]));
  int xs0 = min(min(bx[0], bx[2]), min(bx[4], bx[6]));
  int xe0 = max(max(bx[0], bx[2]), max(bx[4], bx[6]));
  int h = ye0 - ys0, w = xe0 - xs0;

  // reference indexes flattened params by k only (batch-0 params for all i)
  float sig1 = sigp[k * 2 + 1];
  float t0 = tnhp[k * 2 + 0], t1 = tnhp[k * 2 + 1];

  float blur = ((sig1 + 1e-5f) * (float)h) * 0.5f;      // f32 like jnp
  double kfac = 0.75 * sqrt(2.0 * M_PI);                // exact Python f64 path
  int ks = (int)floor((double)blur * kfac + 0.5);
  if (ks < 2) ks = 2;
  if ((ks & 1) == 0) ks += 1;
  int r = ks >> 1, P = r * 3, L = 3 * ks - 2;
  float dxp = (t0 * (float)h) * 0.2f;
  float dyp = (t1 * (float)h) * 0.2f;
  double eh = (double)P + fabs((double)dyp);
  double ew = (double)P + fabs((double)dxp);
  int ys = (int)fmax(fmin((double)ys0 - eh, (double)IMG_H), 0.0);
  int ye = (int)fmax(fmin((double)ye0 + eh, (double)IMG_H), 0.0);
  int xs = (int)fmax(fmin((double)xs0 - ew, (double)IMG_W), 0.0);
  int xe = (int)fmax(fmin((double)xe0 + ew, (double)IMG_W), 0.0);
  int skip = (h < 5 || w < 5) ? 1 : 0;

  if (lane == 0) {
    RegionMeta m;
    m.ys = ys; m.ye = ye; m.xs = xs; m.xe = xe;
    m.skip = skip; m.r = r; m.L = L;
    m.dxp = dxp; m.dyp = dyp;
    m.pad0 = m.pad1 = m.pad2 = 0;
    meta[bid] = m;
  }

  float mean = 0.5f * (float)(ks - 1);
  float inv = 1.0f / (2.0f * blur);
  float gx = 0.f;
  if (lane < ks) { float d = ((float)lane - mean) * inv; gx = expf(-(d * d)); }
  float S = gx;
  #pragma unroll
  for (int off = 32; off > 0; off >>= 1) S += __shfl_xor(S, off);
  __shared__ float gn[64];
  gn[lane] = (lane < ks) ? gx / S : 0.f;
  __syncthreads();

  __shared__ float g2[128];
  for (int a = lane; a < 2 * ks - 1; a += 64) {
    int blo = max(0, a - ks + 1), bhi = min(a, ks - 1);
    float s = 0.f;
    for (int b = blo; b <= bhi; ++b) s += gn[b] * gn[a - b];
    g2[a] = s;
  }
  __syncthreads();

  float* g3 = g3out + (size_t)bid * 256;
  for (int a = lane; a < 256; a += 64) {
    float s = 0.f;
    if (a < L) {
      int blo = max(0, a - (2 * ks - 2)), bhi = min(a, ks - 1);
      for (int b = blo; b <= bhi; ++b) s += gn[b] * g2[a - b];
    }
    g3[a] = s;   // zero-padded beyond L (rolling loops rely on this)
  }
}

// Horizontal pass: block = (region, 3-row group); 256 threads = 3 rows x 76
// chunks of 8 outputs; swizzled LDS row -> conflict-free b128 window reads.
// kk >= 0: fallback (region = z*K+kk, slot z in 0..3). kk == -1: region = z.
__global__ __launch_bounds__(256) void hpass_kernel(const float* __restrict__ alpha,
                             const RegionMeta* __restrict__ meta,
                             const float* __restrict__ g3all,
                             float* __restrict__ tmpH, int kk)
{
  __shared__ __align__(16) float g3s[256];
  __shared__ __align__(16) float srow[3 * 832];
  int z = blockIdx.y;
  int reg = (kk >= 0) ? z * K_CNT + kk : z;
  int i   = (kk >= 0) ? z : z / K_CNT;
  int tid = threadIdx.x;
  RegionMeta m = meta[reg];
  g3s[tid] = g3all[(size_t)reg * 256 + tid];
  int ch = min(m.ye - m.ys, SH), cw = min(m.xe - m.xs, SW);
  int ybase = blockIdx.x * 3;
  int nrows = (!m.skip && ybase < ch) ? min(3, ch - ybase) : 0;
  int P = m.r * 3;
  for (int s = tid; s < nrows * 208; s += 256) {
    int r = s / 208;
    int e = (s - r * 208) * 4;
    const float* row = alpha + ((size_t)i * IMG_H + (m.ys + ybase + r)) * IMG_W + m.xs;
    float4 v; float* vp = (float*)&v;
    #pragma unroll
    for (int u = 0; u < 4; ++u) { int c = e + u - P; vp[u] = (c >= 0 && c < cw) ? row[c] : 0.f; }
    *(float4*)(srow + r * 832 + swz(e)) = v;
  }
  __syncthreads();
  if (!nrows) return;
  int r = tid / 76, c = tid - (tid / 76) * 76;
  int x0 = 8 * c;
  if (r >= nrows || x0 >= cw) return;
  const float* sp = srow + r * 832;
  float w[16], acc[8];
  #pragma unroll
  for (int q = 0; q < 4; ++q) *(float4*)(&w[4 * q]) = *(const float4*)(sp + swz(x0 + 4 * q));
  #pragma unroll
  for (int t = 0; t < 8; ++t) acc[t] = 0.f;
  int Lp = (m.L + 7) & ~7;
  for (int jj = 0; jj < Lp; jj += 16) {
    {
      float ga[8];
      *(float4*)(ga)     = *(const float4*)(g3s + jj);
      *(float4*)(ga + 4) = *(const float4*)(g3s + jj + 4);
      #pragma unroll
      for (int u = 0; u < 8; ++u) {
        float g = ga[u];
        #pragma unroll
        for (int t = 0; t < 8; ++t) acc[t] += g * w[(u + t) & 15];
      }
      *(float4*)(&w[0]) = *(const float4*)(sp + swz(x0 + jj + 16));
      *(float4*)(&w[4]) = *(const float4*)(sp + swz(x0 + jj + 20));
    }
    if (jj + 8 < Lp) {
      float ga[8];
      *(float4*)(ga)     = *(const float4*)(g3s + jj + 8);
      *(float4*)(ga + 4) = *(const float4*)(g3s + jj + 12);
      #pragma unroll
      for (int u = 0; u < 8; ++u) {
        float g = ga[u];
        #pragma unroll
        for (int t = 0; t < 8; ++t) acc[t] += g * w[(8 + u + t) & 15];
      }
      *(float4*)(&w[8])  = *(const float4*)(sp + swz(x0 + jj + 24));
      *(float4*)(&w[12]) = *(const float4*)(sp + swz(x0 + jj + 28));
    }
  }
  float* op = tmpH + (size_t)z * SLOT + (size_t)(ybase + r) * SW + x0;
  *(float4*)op       = make_float4(acc[0], acc[1], acc[2], acc[3]);
  *(float4*)(op + 4) = make_float4(acc[4], acc[5], acc[6], acc[7]);
}

// Vertical pass: 16 consecutive y-outputs per thread via 32-float register
// ring on the global column; guard-free loads except at y-boundaries.
__global__ __launch_bounds__(256) void vpass_kernel(const RegionMeta* __restrict__ meta,
                             const float* __restrict__ g3all,
                             const float* __restrict__ tmpH,
                             float* __restrict__ blurred, int kk)
{
  __shared__ float g3s[256];
  int z = blockIdx.z;
  int reg = (kk >= 0) ? z * K_CNT + kk : z;
  int tid = threadIdx.x;
  RegionMeta m = meta[reg];
  g3s[tid] = g3all[(size_t)reg * 256 + tid];
  __syncthreads();
  if (m.skip) return;
  int ch = min(m.ye - m.ys, SH), cw = min(m.xe - m.xs, SW);
  int x = blockIdx.x * 256 + tid;
  if (x >= cw) return;
  int y0 = blockIdx.y * 16;
  if (y0 >= ch) return;
  int P = m.r * 3;
  int Lp = (m.L + 7) & ~7;
  const float* col = tmpH + (size_t)z * SLOT + x;
  int base = y0 - P;

  float w[32];
  if (base >= 0 && base + 31 < ch) {
    #pragma unroll
    for (int s = 0; s < 32; ++s) w[s] = col[(size_t)(base + s) * SW];
  } else {
    #pragma unroll
    for (int s = 0; s < 32; ++s) {
      int rr = base + s;
      w[s] = (rr >= 0 && rr < ch) ? col[(size_t)rr * SW] : 0.f;
    }
  }
  float acc[16];
  #pragma unroll
  for (int v = 0; v < 16; ++v) acc[v] = 0.f;

  for (int jj = 0; jj < Lp; jj += 32) {
    #define VPH(PH)                                                          \
    if (jj + (PH) < Lp) {                                                    \
      float ga[8];                                                           \
      *(float4*)(ga)     = *(const float4*)(g3s + jj + (PH));                \
      *(float4*)(ga + 4) = *(const float4*)(g3s + jj + (PH) + 4);            \
      _Pragma("unroll")                                                      \
      for (int u = 0; u < 8; ++u) {                                          \
        float g = ga[u];                                                     \
        _Pragma("unroll")                                                    \
        for (int v = 0; v < 16; ++v) acc[v] += g * w[((PH) + u + v) & 31];   \
      }                                                                      \
      int rb = base + jj + (PH) + 32;                                        \
      if (rb >= 0 && rb + 7 < ch) {                                          \
        _Pragma("unroll")                                                    \
        for (int q = 0; q < 8; ++q) w[((PH) + q) & 31] = col[(size_t)(rb + q) * SW]; \
      } else {                                                               \
        _Pragma("unroll")                                                    \
        for (int q = 0; q < 8; ++q) {                                        \
          int rr = rb + q;                                                   \
          w[((PH) + q) & 31] = (rr >= 0 && rr < ch) ? col[(size_t)rr * SW] : 0.f; \
        }                                                                    \
      }                                                                      \
    }
    VPH(0) VPH(8) VPH(16) VPH(24)
    #undef VPH
  }

  float* op = blurred + (size_t)z * SLOT + (size_t)y0 * SW + x;
  #pragma unroll
  for (int v = 0; v < 16; ++v)
    if (y0 + v < ch) op[(size_t)v * SW] = acc[v];
}

// Parallel path: resolve ascending-k overwrite semantics by descending-k scan.
// Wave-level cull: lane k (<8) tests region-k intersection with the wave's
// 64-pixel row segment; __ballot builds the per-wave candidate mask.
__global__ void composite_kernel(const RegionMeta* __restrict__ meta,
                                 const float* __restrict__ blurred,
                                 float* __restrict__ sg, float* __restrict__ sl)
{
  __shared__ RegionMeta ms[32];
  {
    const int* src = (const int*)meta;
    int* dst = (int*)ms;
    for (int a = threadIdx.x; a < 32 * (int)(sizeof(RegionMeta) / 4); a += 256) dst[a] = src[a];
  }
  __syncthreads();
  int idx = blockIdx.x * 256 + threadIdx.x;
  int x = idx & (IMG_W - 1);
  int y = (idx >> 10) & (IMG_H - 1);
  int i = idx >> 20;

  // wave-level candidate mask (wave = 64 contiguous px of one row, same i,y)
  int lane = threadIdx.x & 63;
  int wx0 = x - lane;              // wave's first x (64-aligned)
  bool cov = false;
  if (lane < K_CNT) {
    const RegionMeta& m = ms[i * K_CNT + lane];
    if (!m.skip) {
      int ch = min(m.ye - m.ys, SH), cw = min(m.xe - m.xs, SW);
      cov = (y >= m.ys) && (y < m.ys + ch) && (wx0 + 63 >= m.xs) && (wx0 < m.xs + cw);
    }
  }
  unsigned long long msk = __ballot(cov) & 0xFFull;

  float sgv = 0.f, slv = 0.f;
  bool got = false;
  for (int k = K_CNT - 1; k >= 0; --k) {
    if (!((msk >> k) & 1)) continue;
    const RegionMeta& m = ms[i * K_CNT + k];
    int ch = min(m.ye - m.ys, SH), cw = min(m.xe - m.xs, SW);
    int ly = y - m.ys, lx = x - m.xs;
    if (ly < 0 || ly >= ch || lx < 0 || lx >= cw) continue;
    float sy = (float)ly - m.dyp;
    float sx = (float)lx - m.dxp;
    float x0f = floorf(sx), y0f = floorf(sy);
    float wx = sx - x0f, wy = sy - y0f;
    int x0 = (int)x0f, y0 = (int)y0f;
    const float* bl = blurred + (size_t)(i * K_CNT + k) * SLOT;
    float v00 = (y0 >= 0 && y0 < ch && x0 >= 0 && x0 < cw) ? bl[y0 * SW + x0] : 0.f;
    float v01 = (y0 >= 0 && y0 < ch && x0 + 1 >= 0 && x0 + 1 < cw) ? bl[y0 * SW + x0 + 1] : 0.f;
    float v10 = (y0 + 1 >= 0 && y0 + 1 < ch && x0 >= 0 && x0 < cw) ? bl[(y0 + 1) * SW + x0] : 0.f;
    float v11 = (y0 + 1 >= 0 && y0 + 1 < ch && x0 + 1 >= 0 && x0 + 1 < cw) ? bl[(y0 + 1) * SW + x0 + 1] : 0.f;
    float v = (1.f - wy) * ((1.f - wx) * v00 + wx * v01) + wy * ((1.f - wx) * v10 + wx * v11);
    if (!got) { sgv = v; got = true; }
    if (v > 0.f) { slv = (float)(k + 1); break; }
  }
  sg[idx] = sgv;
  sl[idx] = slv;
}

// Fallback-path bilinear translate + write (ascending-k launches give ordering)
__global__ void shift_kernel(const RegionMeta* __restrict__ meta,
                             const float* __restrict__ blurred,
                             float* __restrict__ sg, float* __restrict__ sl, int k)
{
  int i = blockIdx.y;
  RegionMeta m = meta[i * K_CNT + k];
  if (m.skip) return;
  int ch = min(m.ye - m.ys, SH), cw = min(m.xe - m.xs, SW);
  int idx = blockIdx.x * 256 + threadIdx.x;
  int x = idx % SW, y = idx / SW;
  if (y >= ch || x >= cw) return;
  float sy = (float)y - m.dyp;
  float sx = (float)x - m.dxp;
  float x0f = floorf(sx), y0f = floorf(sy);
  float wx = sx - x0f, wy = sy - y0f;
  int x0 = (int)x0f, y0 = (int)y0f;
  const float* bl = blurred + (size_t)i * SLOT;
  float v00 = (y0 >= 0 && y0 < ch && x0 >= 0 && x0 < cw) ? bl[y0 * SW + x0] : 0.f;
  float v01 = (y0 >= 0 && y0 < ch && x0 + 1 >= 0 && x0 + 1 < cw) ? bl[y0 * SW + x0 + 1] : 0.f;
  float v10 = (y0 + 1 >= 0 && y0 + 1 < ch && x0 >= 0 && x0 < cw) ? bl[(y0 + 1) * SW + x0] : 0.f;
  float v11 = (y0 + 1 >= 0 && y0 + 1 < ch && x0 + 1 >= 0 && x0 + 1 < cw) ? bl[(y0 + 1) * SW + x0 + 1] : 0.f;
  float v = (1.f - wy) * ((1.f - wx) * v00 + wx * v01) + wy * ((1.f - wx) * v10 + wx * v11);
  size_t o = ((size_t)i * IMG_H + (m.ys + y)) * IMG_W + (m.xs + x);
  sg[o] = v;
  if (v > 0.f) sl[o] = (float)(k + 1);
}

extern "C" void kernel_launch(void* const* d_in, const int* in_sizes, int n_in,
                              void* d_out, int out_size, void* d_ws, size_t ws_size,
                              hipStream_t stream) {
  const float* alpha = (const float*)d_in[0];
  // d_in[1] (font_size_pred) is unused by the reference
  const float* sigp = (const float*)d_in[2];
  const float* tnhp = (const float*)d_in[3];
  const int* ta = (const int*)d_in[4];
  float* out = (float*)d_out;

  char* ws = (char*)d_ws;
  RegionMeta* meta = (RegionMeta*)ws;
  float* g3 = (float*)(ws + 4096);

  float* sg = out;
  float* sl = out + (size_t)4 * IMG_H * IMG_W;

  const size_t slotBytes = (size_t)SLOT * 4;
  const size_t needPar = 65536 + 2 * 32 * slotBytes;   // ~42.4 MB

  meta_kernel<<<32, 64, 0, stream>>>(sigp, tnhp, ta, g3, meta);

  if (ws_size >= needPar) {
    // fully parallel across all 32 regions; ordering resolved in composite
    float* tmpH = (float*)(ws + 65536);
    float* blurred = (float*)(ws + 65536 + 32 * slotBytes);
    hpass_kernel<<<dim3(RG_H, 32), 256, 0, stream>>>(alpha, meta, g3, tmpH, -1);
    vpass_kernel<<<dim3(XTILES, YTILES, 32), 256, 0, stream>>>(meta, g3, tmpH, blurred, -1);
    composite_kernel<<<(4 * IMG_H * IMG_W) / 256, 256, 0, stream>>>(meta, blurred, sg, sl);
  } else {
    // fallback: sequential over k (4 regions in parallel), explicit write ordering
    float* tmpH = (float*)(ws + 65536);
    float* blurred = (float*)(ws + 65536 + 4 * slotBytes);
    (void)hipMemsetAsync(d_out, 0, (size_t)out_size * sizeof(float), stream);
    const int blocksPerRegion = (SH * SW) / 256;
    for (int k = 0; k < K_CNT; ++k) {
      hpass_kernel<<<dim3(RG_H, 4), 256, 0, stream>>>(alpha, meta, g3, tmpH, k);
      vpass_kernel<<<dim3(XTILES, YTILES, 4), 256, 0, stream>>>(meta, g3, tmpH, blurred, k);
      shift_kernel<<<dim3(blocksPerRegion, 4), 256, 0, stream>>>(meta, blurred, sg, sl, k);
    }
  }
}

// Round 11
// 84.793 us; speedup vs baseline: 4.2077x; 1.0429x over previous
//
#include <hip/hip_runtime.h>
#include <math.h>

#define K_CNT 8
#define IMG_H 1024
#define IMG_W 1024
#define SW 608            // scratch row stride (floats); max region w = 606
#define SH 272            // scratch rows; max region h = 270
#define SLOT (SW * SH)    // floats per region slot

#define RG_H ((SH + 2) / 3)              // 91 3-row groups per region
#define YTILES ((SH + 15) / 16)          // 17
#define XTILES ((SW + 255) / 256)        // 3

struct RegionMeta {
  int ys, ye, xs, xe;
  int skip, r, L;
  float dxp, dyp;
  int pad0, pad1, pad2;
};

// LDS bank swizzle: XOR f[8:6] into f[4:2]; keeps float4 blocks contiguous,
// spreads the 8-float-stride b128 window reads across bank quads.
__device__ __forceinline__ int swz(int f) { return f ^ ((f >> 6) & 7) * 4; }

// Exact replica of the reference's rect/kernel-size arithmetic (fp32 + fp64
// where Python used fp64). Deterministic; recomputed redundantly per block.
__device__ __forceinline__ void region_calc(const int* bx, float sig1, float t0, float t1,
                                            RegionMeta* mo, float* blur_o, int* ks_o)
{
  int ys0 = min(min(bx[1], bx[3]), min(bx[5], bx[7]));
  int ye0 = max(max(bx[1], bx[3]), max(bx[5], bx[7]));
  int xs0 = min(min(bx[0], bx[2]), min(bx[4], bx[6]));
  int xe0 = max(max(bx[0], bx[2]), max(bx[4], bx[6]));
  int h = ye0 - ys0, w = xe0 - xs0;
  float blur = ((sig1 + 1e-5f) * (float)h) * 0.5f;
  double kfac = 0.75 * sqrt(2.0 * M_PI);
  int ks = (int)floor((double)blur * kfac + 0.5);
  if (ks < 2) ks = 2;
  if ((ks & 1) == 0) ks += 1;
  int r = ks >> 1, P = r * 3, L = 3 * ks - 2;
  float dxp = (t0 * (float)h) * 0.2f;
  float dyp = (t1 * (float)h) * 0.2f;
  double eh = (double)P + fabs((double)dyp);
  double ew = (double)P + fabs((double)dxp);
  RegionMeta m;
  m.ys = (int)fmax(fmin((double)ys0 - eh, (double)IMG_H), 0.0);
  m.ye = (int)fmax(fmin((double)ye0 + eh, (double)IMG_H), 0.0);
  m.xs = (int)fmax(fmin((double)xs0 - ew, (double)IMG_W), 0.0);
  m.xe = (int)fmax(fmin((double)xe0 + ew, (double)IMG_W), 0.0);
  m.skip = (h < 5 || w < 5) ? 1 : 0;
  m.r = r; m.L = L; m.dxp = dxp; m.dyp = dyp;
  m.pad0 = m.pad1 = m.pad2 = 0;
  *mo = m; *blur_o = blur; *ks_o = ks;
}

// Build gn3 = gn*gn*gn into g3s[256] (zero-padded past L). 256-thread blocks.
// gn/g2 are LDS scratch (64 + 128 floats). Ends with a __syncthreads.
__device__ __forceinline__ void build_g3(int ks, float blur, int L,
                                         float* gn, float* g2, float* g3s, int tid)
{
  float mean = 0.5f * (float)(ks - 1);
  float inv = 1.0f / (2.0f * blur);
  if (tid < 64) {
    float gx = 0.f;
    if (tid < ks) { float d = ((float)tid - mean) * inv; gx = expf(-(d * d)); }
    float S = gx;
    #pragma unroll
    for (int off = 32; off > 0; off >>= 1) S += __shfl_xor(S, off);
    gn[tid] = (tid < ks) ? gx / S : 0.f;
  }
  __syncthreads();
  if (tid < 2 * ks - 1) {
    int a = tid;
    int blo = max(0, a - ks + 1), bhi = min(a, ks - 1);
    float s = 0.f;
    for (int b = blo; b <= bhi; ++b) s += gn[b] * gn[a - b];
    g2[a] = s;
  }
  __syncthreads();
  {
    int a = tid;
    float s = 0.f;
    if (a < L) {
      int blo = max(0, a - (2 * ks - 2)), bhi = min(a, ks - 1);
      for (int b = blo; b <= bhi; ++b) s += gn[b] * g2[a - b];
    }
    g3s[a] = s;
  }
  __syncthreads();
}

// Fallback-only meta kernel (shift_kernel needs meta[] in ws).
__global__ void meta_kernel(const float* __restrict__ sigp,
                            const float* __restrict__ tnhp,
                            const int* __restrict__ ta,
                            RegionMeta* __restrict__ meta)
{
  int bid = blockIdx.x * 64 + threadIdx.x;
  if (bid >= 32) return;
  int k = bid & 7;
  int b[8];
  #pragma unroll
  for (int u = 0; u < 8; ++u) b[u] = ta[bid * 8 + u];
  RegionMeta m; float blur; int ks;
  region_calc(b, sigp[k * 2 + 1], tnhp[k * 2], tnhp[k * 2 + 1], &m, &blur, &ks);
  meta[bid] = m;
}

// Horizontal pass: block = (region, 3-row group); 256 threads = 3 rows x 76
// chunks of 8 outputs; swizzled LDS row -> conflict-free b128 window reads.
// Self-computes meta + g3. kk >= 0: fallback (region = z*K+kk). kk == -1: region = z.
__global__ __launch_bounds__(256) void hpass_kernel(const float* __restrict__ alpha,
                             const float* __restrict__ sigp,
                             const float* __restrict__ tnhp,
                             const int* __restrict__ ta,
                             float* __restrict__ tmpH, int kk)
{
  __shared__ __align__(16) float g3s[256];
  __shared__ __align__(16) float srow[3 * 832];
  __shared__ int bx[8];
  int z = blockIdx.y;
  int reg = (kk >= 0) ? z * K_CNT + kk : z;
  int i   = (kk >= 0) ? z : z / K_CNT;
  int k   = reg & 7;
  int tid = threadIdx.x;
  if (tid < 8) bx[tid] = ta[reg * 8 + tid];
  __syncthreads();
  RegionMeta m; float blur; int ks;
  region_calc(bx, sigp[k * 2 + 1], tnhp[k * 2], tnhp[k * 2 + 1], &m, &blur, &ks);
  build_g3(ks, blur, m.L, srow, srow + 64, g3s, tid);   // srow as scratch; syncs

  int ch = min(m.ye - m.ys, SH), cw = min(m.xe - m.xs, SW);
  int ybase = blockIdx.x * 3;
  int nrows = (!m.skip && ybase < ch) ? min(3, ch - ybase) : 0;
  int P = m.r * 3;
  for (int s = tid; s < nrows * 208; s += 256) {
    int r = s / 208;
    int e = (s - r * 208) * 4;
    const float* row = alpha + ((size_t)i * IMG_H + (m.ys + ybase + r)) * IMG_W + m.xs;
    float4 v; float* vp = (float*)&v;
    #pragma unroll
    for (int u = 0; u < 4; ++u) { int c = e + u - P; vp[u] = (c >= 0 && c < cw) ? row[c] : 0.f; }
    *(float4*)(srow + r * 832 + swz(e)) = v;
  }
  __syncthreads();
  if (!nrows) return;
  int r = tid / 76, c = tid - (tid / 76) * 76;
  int x0 = 8 * c;
  if (r >= nrows || x0 >= cw) return;
  const float* sp = srow + r * 832;
  float w[16], acc[8];
  #pragma unroll
  for (int q = 0; q < 4; ++q) *(float4*)(&w[4 * q]) = *(const float4*)(sp + swz(x0 + 4 * q));
  #pragma unroll
  for (int t = 0; t < 8; ++t) acc[t] = 0.f;
  int Lp = (m.L + 7) & ~7;
  for (int jj = 0; jj < Lp; jj += 16) {
    {
      float ga[8];
      *(float4*)(ga)     = *(const float4*)(g3s + jj);
      *(float4*)(ga + 4) = *(const float4*)(g3s + jj + 4);
      #pragma unroll
      for (int u = 0; u < 8; ++u) {
        float g = ga[u];
        #pragma unroll
        for (int t = 0; t < 8; ++t) acc[t] += g * w[(u + t) & 15];
      }
      *(float4*)(&w[0]) = *(const float4*)(sp + swz(x0 + jj + 16));
      *(float4*)(&w[4]) = *(const float4*)(sp + swz(x0 + jj + 20));
    }
    if (jj + 8 < Lp) {
      float ga[8];
      *(float4*)(ga)     = *(const float4*)(g3s + jj + 8);
      *(float4*)(ga + 4) = *(const float4*)(g3s + jj + 12);
      #pragma unroll
      for (int u = 0; u < 8; ++u) {
        float g = ga[u];
        #pragma unroll
        for (int t = 0; t < 8; ++t) acc[t] += g * w[(8 + u + t) & 15];
      }
      *(float4*)(&w[8])  = *(const float4*)(sp + swz(x0 + jj + 24));
      *(float4*)(&w[12]) = *(const float4*)(sp + swz(x0 + jj + 28));
    }
  }
  float* op = tmpH + (size_t)z * SLOT + (size_t)(ybase + r) * SW + x0;
  *(float4*)op       = make_float4(acc[0], acc[1], acc[2], acc[3]);
  *(float4*)(op + 4) = make_float4(acc[4], acc[5], acc[6], acc[7]);
}

// Vertical pass: 16 consecutive y-outputs per thread via 32-float register
// ring on the global column. Self-computes meta + g3.
__global__ __launch_bounds__(256) void vpass_kernel(const float* __restrict__ sigp,
                             const float* __restrict__ tnhp,
                             const int* __restrict__ ta,
                             const float* __restrict__ tmpH,
                             float* __restrict__ blurred, int kk)
{
  __shared__ __align__(16) float g3s[256];
  __shared__ __align__(16) float scr[192];
  __shared__ int bx[8];
  int z = blockIdx.z;
  int reg = (kk >= 0) ? z * K_CNT + kk : z;
  int k   = reg & 7;
  int tid = threadIdx.x;
  if (tid < 8) bx[tid] = ta[reg * 8 + tid];
  __syncthreads();
  RegionMeta m; float blur; int ks;
  region_calc(bx, sigp[k * 2 + 1], tnhp[k * 2], tnhp[k * 2 + 1], &m, &blur, &ks);
  build_g3(ks, blur, m.L, scr, scr + 64, g3s, tid);

  if (m.skip) return;
  int ch = min(m.ye - m.ys, SH), cw = min(m.xe - m.xs, SW);
  int x = blockIdx.x * 256 + tid;
  if (x >= cw) return;
  int y0 = blockIdx.y * 16;
  if (y0 >= ch) return;
  int P = m.r * 3;
  int Lp = (m.L + 7) & ~7;
  const float* col = tmpH + (size_t)z * SLOT + x;
  int base = y0 - P;

  float w[32];
  if (base >= 0 && base + 31 < ch) {
    #pragma unroll
    for (int s = 0; s < 32; ++s) w[s] = col[(size_t)(base + s) * SW];
  } else {
    #pragma unroll
    for (int s = 0; s < 32; ++s) {
      int rr = base + s;
      w[s] = (rr >= 0 && rr < ch) ? col[(size_t)rr * SW] : 0.f;
    }
  }
  float acc[16];
  #pragma unroll
  for (int v = 0; v < 16; ++v) acc[v] = 0.f;

  for (int jj = 0; jj < Lp; jj += 32) {
    #define VPH(PH)                                                          \
    if (jj + (PH) < Lp) {                                                    \
      float ga[8];                                                           \
      *(float4*)(ga)     = *(const float4*)(g3s + jj + (PH));                \
      *(float4*)(ga + 4) = *(const float4*)(g3s + jj + (PH) + 4);            \
      _Pragma("unroll")                                                      \
      for (int u = 0; u < 8; ++u) {                                          \
        float g = ga[u];                                                     \
        _Pragma("unroll")                                                    \
        for (int v = 0; v < 16; ++v) acc[v] += g * w[((PH) + u + v) & 31];   \
      }                                                                      \
      int rb = base + jj + (PH) + 32;                                        \
      if (rb >= 0 && rb + 7 < ch) {                                          \
        _Pragma("unroll")                                                    \
        for (int q = 0; q < 8; ++q) w[((PH) + q) & 31] = col[(size_t)(rb + q) * SW]; \
      } else {                                                               \
        _Pragma("unroll")                                                    \
        for (int q = 0; q < 8; ++q) {                                        \
          int rr = rb + q;                                                   \
          w[((PH) + q) & 31] = (rr >= 0 && rr < ch) ? col[(size_t)rr * SW] : 0.f; \
        }                                                                    \
      }                                                                      \
    }
    VPH(0) VPH(8) VPH(16) VPH(24)
    #undef VPH
  }

  float* op = blurred + (size_t)z * SLOT + (size_t)y0 * SW + x;
  #pragma unroll
  for (int v = 0; v < 16; ++v)
    if (y0 + v < ch) op[(size_t)v * SW] = acc[v];
}

// Parallel path: resolve ascending-k overwrite semantics by descending-k scan.
// 4 px/thread, float4 writes; wave-level cull over a 256-px row chunk.
// Lanes 0-31 self-compute the 32 region rects.
__global__ __launch_bounds__(256) void composite_kernel(const float* __restrict__ sigp,
                                 const float* __restrict__ tnhp,
                                 const int* __restrict__ ta,
                                 const float* __restrict__ blurred,
                                 float* __restrict__ sg, float* __restrict__ sl)
{
  __shared__ RegionMeta ms[32];
  int tid = threadIdx.x;
  if (tid < 32) {
    int b[8];
    #pragma unroll
    for (int u = 0; u < 8; ++u) b[u] = ta[tid * 8 + u];
    int k = tid & 7;
    RegionMeta m; float blur; int ks;
    region_calc(b, sigp[k * 2 + 1], tnhp[k * 2], tnhp[k * 2 + 1], &m, &blur, &ks);
    ms[tid] = m;
  }
  __syncthreads();
  int gid = blockIdx.x * 256 + tid;
  int base = gid * 4;
  int x = base & (IMG_W - 1);
  int y = (base >> 10) & (IMG_H - 1);
  int i = base >> 20;

  // wave covers 256 contiguous px of one row (same i, y)
  int lane = tid & 63;
  int wx0 = x & ~255;
  bool cov = false;
  if (lane < K_CNT) {
    const RegionMeta& m = ms[i * K_CNT + lane];
    if (!m.skip) {
      int ch = min(m.ye - m.ys, SH), cw = min(m.xe - m.xs, SW);
      cov = (y >= m.ys) && (y < m.ys + ch) && (wx0 + 255 >= m.xs) && (wx0 < m.xs + cw);
    }
  }
  unsigned long long msk = __ballot(cov) & 0xFFull;

  float4 sg4 = make_float4(0.f, 0.f, 0.f, 0.f);
  float4 sl4 = make_float4(0.f, 0.f, 0.f, 0.f);
  if (msk) {
    float* sgp_ = (float*)&sg4;
    float* slp_ = (float*)&sl4;
    #pragma unroll
    for (int p = 0; p < 4; ++p) {
      int xp = x + p;
      float sgv = 0.f, slv = 0.f;
      bool got = false;
      for (int k = K_CNT - 1; k >= 0; --k) {
        if (!((msk >> k) & 1)) continue;
        const RegionMeta& m = ms[i * K_CNT + k];
        int ch = min(m.ye - m.ys, SH), cw = min(m.xe - m.xs, SW);
        int ly = y - m.ys, lx = xp - m.xs;
        if (ly < 0 || ly >= ch || lx < 0 || lx >= cw) continue;
        float sy = (float)ly - m.dyp;
        float sx = (float)lx - m.dxp;
        float x0f = floorf(sx), y0f = floorf(sy);
        float wx = sx - x0f, wy = sy - y0f;
        int x0 = (int)x0f, y0 = (int)y0f;
        const float* bl = blurred + (size_t)(i * K_CNT + k) * SLOT;
        float v00 = (y0 >= 0 && y0 < ch && x0 >= 0 && x0 < cw) ? bl[y0 * SW + x0] : 0.f;
        float v01 = (y0 >= 0 && y0 < ch && x0 + 1 >= 0 && x0 + 1 < cw) ? bl[y0 * SW + x0 + 1] : 0.f;
        float v10 = (y0 + 1 >= 0 && y0 + 1 < ch && x0 >= 0 && x0 < cw) ? bl[(y0 + 1) * SW + x0] : 0.f;
        float v11 = (y0 + 1 >= 0 && y0 + 1 < ch && x0 + 1 >= 0 && x0 + 1 < cw) ? bl[(y0 + 1) * SW + x0 + 1] : 0.f;
        float v = (1.f - wy) * ((1.f - wx) * v00 + wx * v01) + wy * ((1.f - wx) * v10 + wx * v11);
        if (!got) { sgv = v; got = true; }
        if (v > 0.f) { slv = (float)(k + 1); break; }
      }
      sgp_[p] = sgv;
      slp_[p] = slv;
    }
  }
  *(float4*)(sg + base) = sg4;
  *(float4*)(sl + base) = sl4;
}

// Fallback-path bilinear translate + write (ascending-k launches give ordering)
__global__ void shift_kernel(const RegionMeta* __restrict__ meta,
                             const float* __restrict__ blurred,
                             float* __restrict__ sg, float* __restrict__ sl, int k)
{
  int i = blockIdx.y;
  RegionMeta m = meta[i * K_CNT + k];
  if (m.skip) return;
  int ch = min(m.ye - m.ys, SH), cw = min(m.xe - m.xs, SW);
  int idx = blockIdx.x * 256 + threadIdx.x;
  int x = idx % SW, y = idx / SW;
  if (y >= ch || x >= cw) return;
  float sy = (float)y - m.dyp;
  float sx = (float)x - m.dxp;
  float x0f = floorf(sx), y0f = floorf(sy);
  float wx = sx - x0f, wy = sy - y0f;
  int x0 = (int)x0f, y0 = (int)y0f;
  const float* bl = blurred + (size_t)i * SLOT;
  float v00 = (y0 >= 0 && y0 < ch && x0 >= 0 && x0 < cw) ? bl[y0 * SW + x0] : 0.f;
  float v01 = (y0 >= 0 && y0 < ch && x0 + 1 >= 0 && x0 + 1 < cw) ? bl[y0 * SW + x0 + 1] : 0.f;
  float v10 = (y0 + 1 >= 0 && y0 + 1 < ch && x0 >= 0 && x0 < cw) ? bl[(y0 + 1) * SW + x0] : 0.f;
  float v11 = (y0 + 1 >= 0 && y0 + 1 < ch && x0 + 1 >= 0 && x0 + 1 < cw) ? bl[(y0 + 1) * SW + x0 + 1] : 0.f;
  float v = (1.f - wy) * ((1.f - wx) * v00 + wx * v01) + wy * ((1.f - wx) * v10 + wx * v11);
  size_t o = ((size_t)i * IMG_H + (m.ys + y)) * IMG_W + (m.xs + x);
  sg[o] = v;
  if (v > 0.f) sl[o] = (float)(k + 1);
}

extern "C" void kernel_launch(void* const* d_in, const int* in_sizes, int n_in,
                              void* d_out, int out_size, void* d_ws, size_t ws_size,
                              hipStream_t stream) {
  const float* alpha = (const float*)d_in[0];
  // d_in[1] (font_size_pred) is unused by the reference
  const float* sigp = (const float*)d_in[2];
  const float* tnhp = (const float*)d_in[3];
  const int* ta = (const int*)d_in[4];
  float* out = (float*)d_out;

  char* ws = (char*)d_ws;
  RegionMeta* meta = (RegionMeta*)ws;

  float* sg = out;
  float* sl = out + (size_t)4 * IMG_H * IMG_W;

  const size_t slotBytes = (size_t)SLOT * 4;
  const size_t needPar = 65536 + 2 * 32 * slotBytes;   // ~42.4 MB

  if (ws_size >= needPar) {
    // fully parallel across all 32 regions; ordering resolved in composite;
    // meta + g3 self-computed per block (no serial meta kernel)
    float* tmpH = (float*)(ws + 65536);
    float* blurred = (float*)(ws + 65536 + 32 * slotBytes);
    hpass_kernel<<<dim3(RG_H, 32), 256, 0, stream>>>(alpha, sigp, tnhp, ta, tmpH, -1);
    vpass_kernel<<<dim3(XTILES, YTILES, 32), 256, 0, stream>>>(sigp, tnhp, ta, tmpH, blurred, -1);
    composite_kernel<<<(4 * IMG_H * IMG_W) / 1024, 256, 0, stream>>>(sigp, tnhp, ta, blurred, sg, sl);
  } else {
    // fallback: sequential over k (4 regions in parallel), explicit write ordering
    float* tmpH = (float*)(ws + 65536);
    float* blurred = (float*)(ws + 65536 + 4 * slotBytes);
    meta_kernel<<<1, 64, 0, stream>>>(sigp, tnhp, ta, meta);
    (void)hipMemsetAsync(d_out, 0, (size_t)out_size * sizeof(float), stream);
    const int blocksPerRegion = (SH * SW) / 256;
    for (int k = 0; k < K_CNT; ++k) {
      hpass_kernel<<<dim3(RG_H, 4), 256, 0, stream>>>(alpha, sigp, tnhp, ta, tmpH, k);
      vpass_kernel<<<dim3(XTILES, YTILES, 4), 256, 0, stream>>>(sigp, tnhp, ta, tmpH, blurred, k);
      shift_kernel<<<dim3(blocksPerRegion, 4), 256, 0, stream>>>(meta, blurred, sg, sl, k);
    }
  }
}